// Round 7
// baseline (531.725 us; speedup 1.0000x reference)
//
#include <hip/hip_runtime.h>
#include <math.h>

typedef unsigned int u32;
typedef unsigned short ushort_t;
typedef __attribute__((ext_vector_type(8))) short short8;
typedef __attribute__((ext_vector_type(4))) float f32x4;

__device__ __forceinline__ ushort_t f2bf(float x) {
  u32 u = __float_as_uint(x);
  u32 r = (u + 0x7fffu + ((u >> 16) & 1u)) >> 16;
  return (ushort_t)r;
}
__device__ __forceinline__ float bf2f(u32 s) {
  return __uint_as_float(s << 16);
}
__device__ __forceinline__ void ld4bf(const ushort_t* p, float* o) {
  uint2 u = *(const uint2*)p;
  o[0] = bf2f(u.x & 0xffffu); o[1] = bf2f(u.x >> 16);
  o[2] = bf2f(u.y & 0xffffu); o[3] = bf2f(u.y >> 16);
}

// ---------------- block reduction helpers (256 threads = 4 waves) ----------
__device__ __forceinline__ float block_sum256(float v, float* red) {
  #pragma unroll
  for (int o = 32; o > 0; o >>= 1) v += __shfl_down(v, o, 64);
  __syncthreads();
  if ((threadIdx.x & 63) == 0) red[threadIdx.x >> 6] = v;
  __syncthreads();
  return red[0] + red[1] + red[2] + red[3];
}

// =====================================================================
// 256x256-tile, 8-phase, counted-vmcnt MFMA GEMM (m201-style schedule).
// C[m,n] (op)= scale * sum_k A[m,k]*B[n,k];  A:[M,K] bf16, B:[N,K] bf16.
// BK=64, K/zsplit % 128 == 0. 512 thr = 8 waves (2M x 4N), 128 KiB LDS.
// zsplit>1: grid.z = K-split, C += z*zC. zsplit==1: grid.z = batch (zA/zB/zC).
// bShift>=0: B += (m0>>bShift)*bHead (per-m-tile head select).
// CMODE: 0 = store f32 (+RELU), 1 = store bf16 via LDS-transposed coalesced
//        epilogue, 2 = atomicAdd f32.
// EXPSUM: v=exp(v*scale) before store; row-sums atomic into Rs[z*4096+gm].
// =====================================================================
#define RD_A(bb, mm, cc) (*(const short8*)(lsAc + (bb)*32768 + arow + (mm)*2048 + (cc)))
#define RD_B(bb, nn, cc) (*(const short8*)(lsBc + (bb)*32768 + brow + (nn)*2048 + (cc)))

#define MM8(nn, bv) { \
  acc[0][nn] = __builtin_amdgcn_mfma_f32_16x16x32_bf16(a0, bv, acc[0][nn], 0,0,0); \
  acc[1][nn] = __builtin_amdgcn_mfma_f32_16x16x32_bf16(a1, bv, acc[1][nn], 0,0,0); \
  acc[2][nn] = __builtin_amdgcn_mfma_f32_16x16x32_bf16(a2, bv, acc[2][nn], 0,0,0); \
  acc[3][nn] = __builtin_amdgcn_mfma_f32_16x16x32_bf16(a3, bv, acc[3][nn], 0,0,0); \
  acc[4][nn] = __builtin_amdgcn_mfma_f32_16x16x32_bf16(a4, bv, acc[4][nn], 0,0,0); \
  acc[5][nn] = __builtin_amdgcn_mfma_f32_16x16x32_bf16(a5, bv, acc[5][nn], 0,0,0); \
  acc[6][nn] = __builtin_amdgcn_mfma_f32_16x16x32_bf16(a6, bv, acc[6][nn], 0,0,0); \
  acc[7][nn] = __builtin_amdgcn_mfma_f32_16x16x32_bf16(a7, bv, acc[7][nn], 0,0,0); }

#define STG(BASE, LD, LS, bb, hf, tt) { \
  _Pragma("unroll") \
  for (int ii = 0; ii < 2; ++ii) { \
    const int s_ = t + ii * 512; \
    const int r_ = s_ >> 3; \
    const int lc_ = (s_ & 7) ^ (r_ & 7); \
    __builtin_amdgcn_global_load_lds( \
      (const __attribute__((address_space(1))) u32*)((BASE) + (size_t)((hf) * 128 + r_) * (LD) + (size_t)(tt) * 64 + lc_ * 8), \
      (__attribute__((address_space(3))) u32*)(&(LS)[bb][(hf) * 8192 + s_ * 8]), 16, 0, 0); \
  } }

#define BAR() __builtin_amdgcn_s_barrier()
#define PRIO(x) __builtin_amdgcn_s_setprio(x)

#define GRP(bf, tS1, tS2) { \
  a0=RD_A(bf,0,c0); a1=RD_A(bf,1,c0); a2=RD_A(bf,2,c0); a3=RD_A(bf,3,c0); \
  a4=RD_A(bf,4,c0); a5=RD_A(bf,5,c0); a6=RD_A(bf,6,c0); a7=RD_A(bf,7,c0); \
  b0=RD_B(bf,0,c0); b1=RD_B(bf,1,c0); \
  STG(Ab, lda, lsA, 1-(bf), 1, tS1); STG(Bb, ldb, lsB, 1-(bf), 0, tS1); \
  BAR(); PRIO(1); MM8(0, b0); MM8(1, b1); PRIO(0); BAR(); \
  b2=RD_B(bf,2,c0); b3=RD_B(bf,3,c0); \
  STG(Bb, ldb, lsB, 1-(bf), 1, tS1); \
  BAR(); PRIO(1); MM8(2, b2); MM8(3, b3); PRIO(0); BAR(); \
  a0=RD_A(bf,0,c1); a1=RD_A(bf,1,c1); a2=RD_A(bf,2,c1); a3=RD_A(bf,3,c1); \
  a4=RD_A(bf,4,c1); a5=RD_A(bf,5,c1); a6=RD_A(bf,6,c1); a7=RD_A(bf,7,c1); \
  b0=RD_B(bf,0,c1); b1=RD_B(bf,1,c1); \
  BAR(); PRIO(1); MM8(0, b0); MM8(1, b1); PRIO(0); BAR(); \
  b2=RD_B(bf,2,c1); b3=RD_B(bf,3,c1); \
  STG(Ab, lda, lsA, (bf), 0, tS2); \
  BAR(); PRIO(1); MM8(2, b2); MM8(3, b3); PRIO(0); \
  asm volatile("s_waitcnt vmcnt(2)" ::: "memory"); \
  BAR(); }

template<int CMODE, bool RELU, bool EXPSUM>
__global__ __launch_bounds__(512, 2) void mfma256_8ph(
    const ushort_t* __restrict__ A, const ushort_t* __restrict__ B,
    void* __restrict__ Cv, int lda, int ldb, int ldc,
    int K, int zsplit, size_t zA, size_t zB, size_t zC,
    int bShift, size_t bHead, int Mvalid, float scale,
    float* __restrict__ Rs)
{
  __shared__ ushort_t lsA[2][16384];
  __shared__ ushort_t lsB[2][16384];
  const int t = threadIdx.x;
  const int gx = gridDim.x;
  const int nwg = gx * gridDim.y;
  const int bid = blockIdx.y * gx + blockIdx.x;
  const int qq = nwg >> 3, rr_ = nwg & 7;
  const int xcd = bid & 7, idx = bid >> 3;
  const int swz = (xcd < rr_ ? xcd * (qq + 1) : rr_ * (qq + 1) + (xcd - rr_) * qq) + idx;
  const int m0 = (swz / gx) * 256;
  const int n0 = (swz % gx) * 256;
  const int z = blockIdx.z;
  int Kc = K, kOff = 0;
  size_t aZ = 0, bZ = 0, cZ = 0;
  if (zsplit > 1) { Kc = K / zsplit; kOff = z * Kc; cZ = (size_t)z * zC; }
  else { aZ = (size_t)z * zA; bZ = (size_t)z * zB; cZ = (size_t)z * zC; }
  const ushort_t* Ab = A + aZ + (size_t)m0 * lda + kOff;
  const ushort_t* Bb = B + bZ + (size_t)n0 * ldb + kOff
                     + (bShift >= 0 ? (size_t)(m0 >> bShift) * bHead : 0);
  const int NT = Kc / 64;

  f32x4 acc[8][4];
  #pragma unroll
  for (int i = 0; i < 8; ++i)
    #pragma unroll
    for (int j = 0; j < 4; ++j) acc[i][j] = (f32x4){0.f, 0.f, 0.f, 0.f};

  const int lane = t & 63;
  const int wv = t >> 6;
  const int wr = (wv >> 2) * 128;
  const int wc = (wv & 3) * 64;
  const int lr = lane & 15;
  const int kc = lane >> 4;
  const int sw = lane & 7;
  const int c0 = (kc ^ sw) * 16;
  const int c1 = c0 ^ 64;
  const int arow = (wr + lr) * 128;
  const int brow = (wc + lr) * 128;
  const char* lsAc = (const char*)lsA;
  const char* lsBc = (const char*)lsB;

  short8 a0, a1, a2, a3, a4, a5, a6, a7, b0, b1, b2, b3;

  STG(Ab, lda, lsA, 0, 0, 0); STG(Ab, lda, lsA, 0, 1, 0);
  STG(Bb, ldb, lsB, 0, 0, 0); STG(Bb, ldb, lsB, 0, 1, 0);
  STG(Ab, lda, lsA, 1, 0, 1);
  asm volatile("s_waitcnt vmcnt(2)" ::: "memory");
  BAR();

  const int NITER = NT >> 1;
  for (int it = 0; it < NITER; ++it) {
    const int tb = 2 * it;
    const int s1 = tb + 1;
    const int s2 = (tb + 2 < NT) ? tb + 2 : 0;
    const int s3 = (tb + 3 < NT) ? tb + 3 : 0;
    GRP(0, s1, s2)
    GRP(1, s2, s3)
  }

  const int row4 = (lane >> 4) * 4;
  const int coln = lane & 15;
  float* Cf = (float*)Cv + cZ;
  ushort_t* Ch = (ushort_t*)Cv + cZ;
  float* rs = EXPSUM ? (Rs + (size_t)z * 4096) : nullptr;

  if (CMODE == 1) {
    // ---- LDS-transposed coalesced bf16 epilogue ----
    asm volatile("s_waitcnt vmcnt(0)" ::: "memory");  // drain tail staging loads
    __syncthreads();
    ushort_t* sb = (wr == 0) ? &lsA[0][0] : &lsB[0][0];  // 128 rows x 256 cols
    #pragma unroll
    for (int m = 0; m < 8; ++m) {
      #pragma unroll
      for (int r = 0; r < 4; ++r) {
        const int lrow = m * 16 + row4 + r;       // 0..127 within half
        const int gm = m0 + wr + lrow;
        float rowpart = 0.f;
        #pragma unroll
        for (int n = 0; n < 4; ++n) {
          float v = acc[m][n][r] * scale;
          if (EXPSUM) { v = __expf(v); rowpart += v; }
          sb[lrow * 256 + wc + n * 16 + coln] = f2bf(v);
        }
        if (EXPSUM) {
          rowpart += __shfl_xor(rowpart, 1);
          rowpart += __shfl_xor(rowpart, 2);
          rowpart += __shfl_xor(rowpart, 4);
          rowpart += __shfl_xor(rowpart, 8);
          if ((lane & 15) == 0 && gm < Mvalid) atomicAdd(&rs[gm], rowpart);
        }
      }
    }
    __syncthreads();
    #pragma unroll
    for (int i = 0; i < 16; ++i) {
      const int u = t + i * 512;
      const int row = u >> 5;            // 0..255 (rows 16i..16i+15)
      const int cu = u & 31;
      const int gm = m0 + row;
      const ushort_t* src = (i < 8) ? &lsA[0][0] : &lsB[0][0];
      const int lr2 = row & 127;
      if (gm < Mvalid) {
        uint4 d = *(const uint4*)(src + lr2 * 256 + cu * 8);
        *(uint4*)(Ch + (size_t)gm * ldc + n0 + cu * 8) = d;
      }
    }
  } else {
    #pragma unroll
    for (int m = 0; m < 8; ++m) {
      #pragma unroll
      for (int r = 0; r < 4; ++r) {
        const int gm = m0 + wr + m * 16 + row4 + r;
        const bool ok = gm < Mvalid;
        #pragma unroll
        for (int n = 0; n < 4; ++n) {
          const int gn = n0 + wc + n * 16 + coln;
          float v = acc[m][n][r] * scale;
          if (RELU) v = fmaxf(v, 0.f);
          if (ok) {
            if (CMODE == 0) Cf[(size_t)gm * ldc + gn] = v;
            else            atomicAdd(&Cf[(size_t)gm * ldc + gn], v);
          }
        }
      }
    }
  }
}

#undef GRP
#undef STG
#undef MM8
#undef RD_A
#undef RD_B

// ================= 128x128-tile MFMA GEMM, 256 threads =====================
template<int CMODE, bool RELU, bool EXPSUM>
__global__ __launch_bounds__(256) void mfma_bt(
    const ushort_t* __restrict__ A, const ushort_t* __restrict__ B,
    void* __restrict__ Cv, int lda, int ldb, int ldc,
    int K, int Ksplit, size_t zA, size_t zB, size_t zC,
    int bShift, size_t bHead, int mMask, int Mvalid, float scale,
    float* __restrict__ Rs)
{
  __shared__ ushort_t lsA[2][128 * 32];
  __shared__ ushort_t lsB[2][128 * 32];
  const int t  = threadIdx.x;
  const int m0 = blockIdx.y * 128;
  const int n0 = blockIdx.x * 128;
  const int z = blockIdx.z;
  int Kc = K, kOff = 0;
  size_t aZ = 0, bZ = 0, cZ = 0;
  if (Ksplit > 1) { Kc = K / Ksplit; kOff = z * Kc; cZ = (size_t)z * zC; }
  else { aZ = (size_t)z * zA; bZ = (size_t)z * zB; cZ = (size_t)z * zC; }
  const int NT = Kc / 32;
  const ushort_t* Ab = A + aZ + (size_t)m0 * lda + kOff;
  const ushort_t* Bb = B + bZ + (size_t)n0 * ldb + kOff
                     + (bShift >= 0 ? (size_t)(m0 >> bShift) * bHead : 0);
  const int cs = t & 3;

  f32x4 acc[4][4];
  #pragma unroll
  for (int i = 0; i < 4; ++i)
    #pragma unroll
    for (int j = 0; j < 4; ++j) acc[i][j] = (f32x4){0.f, 0.f, 0.f, 0.f};

  const int lane = t & 63;
  const int wv = t >> 6;
  const int wr = (wv >> 1) * 64;
  const int wc = (wv & 1) * 64;
  const int lr = lane & 15;
  const int kc = lane >> 4;

  int roffA[4], roffB[4];
  #pragma unroll
  for (int m = 0; m < 4; ++m) {
    int ra = wr + m * 16 + lr;
    roffA[m] = ra * 64 + ((kc ^ (ra & 3)) * 16);
    int rb = wc + m * 16 + lr;
    roffB[m] = rb * 64 + ((kc ^ (rb & 3)) * 16);
  }

  auto stage = [&](int buf, int kt) {
    const ushort_t* As = Ab + kt * 32;
    const ushort_t* Bs = Bb + kt * 32;
    #pragma unroll
    for (int i = 0; i < 2; ++i) {
      int s = t + i * 256;
      int r = s >> 2;
      int c = cs ^ (r & 3);
      __builtin_amdgcn_global_load_lds(
          (const __attribute__((address_space(1))) u32*)(As + (size_t)r * lda + c * 8),
          (__attribute__((address_space(3))) u32*)(&lsA[buf][s * 8]), 16, 0, 0);
    }
    #pragma unroll
    for (int i = 0; i < 2; ++i) {
      int s = t + i * 256;
      int r = s >> 2;
      int c = cs ^ (r & 3);
      __builtin_amdgcn_global_load_lds(
          (const __attribute__((address_space(1))) u32*)(Bs + (size_t)r * ldb + c * 8),
          (__attribute__((address_space(3))) u32*)(&lsB[buf][s * 8]), 16, 0, 0);
    }
  };

  stage(0, 0);
  __syncthreads();
  int cur = 0;
  for (int kt = 0; kt < NT; ++kt) {
    if (kt + 1 < NT) stage(cur ^ 1, kt + 1);
    short8 af[4], bfr[4];
    const char* baseA = (const char*)&lsA[cur][0];
    const char* baseB = (const char*)&lsB[cur][0];
    #pragma unroll
    for (int m = 0; m < 4; ++m) af[m]  = *(const short8*)(baseA + roffA[m]);
    #pragma unroll
    for (int n = 0; n < 4; ++n) bfr[n] = *(const short8*)(baseB + roffB[n]);
    #pragma unroll
    for (int m = 0; m < 4; ++m)
      #pragma unroll
      for (int n = 0; n < 4; ++n)
        acc[m][n] = __builtin_amdgcn_mfma_f32_16x16x32_bf16(af[m], bfr[n], acc[m][n], 0, 0, 0);
    __syncthreads();
    cur ^= 1;
  }

  const int row4 = (lane >> 4) * 4;
  const int coln = lane & 15;
  float* Cf = (float*)Cv + cZ;
  ushort_t* Ch = (ushort_t*)Cv + cZ;
  float* rs = EXPSUM ? (Rs + (size_t)z * 4096) : nullptr;

  if (CMODE == 1) {
    // ---- LDS-transposed coalesced bf16 epilogue (128x128 tile) ----
    ushort_t* sb = (wr == 0) ? &lsA[0][0] : &lsB[0][0];  // 64 rows x 128 cols
    #pragma unroll
    for (int m = 0; m < 4; ++m) {
      #pragma unroll
      for (int r = 0; r < 4; ++r) {
        const int lrow = m * 16 + row4 + r;        // 0..63 within half
        const int gm = m0 + wr + lrow;
        float rowpart = 0.f;
        #pragma unroll
        for (int n = 0; n < 4; ++n) {
          float v = acc[m][n][r] * scale;
          if (EXPSUM) { v = __expf(v); rowpart += v; }
          sb[lrow * 128 + wc + n * 16 + coln] = f2bf(v);
        }
        if (EXPSUM) {
          rowpart += __shfl_xor(rowpart, 1);
          rowpart += __shfl_xor(rowpart, 2);
          rowpart += __shfl_xor(rowpart, 4);
          rowpart += __shfl_xor(rowpart, 8);
          if ((lane & 15) == 0 && gm < Mvalid) atomicAdd(&rs[gm], rowpart);
        }
      }
    }
    __syncthreads();
    #pragma unroll
    for (int i = 0; i < 8; ++i) {
      const int u = t + i * 256;
      const int row = u >> 4;            // 0..127 (rows 16i..16i+15)
      const int cu = u & 15;
      const int gm = m0 + row;
      const ushort_t* src = (i < 4) ? &lsA[0][0] : &lsB[0][0];
      const int lr2 = row & 63;
      if (gm < Mvalid) {
        uint4 d = *(const uint4*)(src + lr2 * 128 + cu * 8);
        *(uint4*)(Ch + (size_t)gm * ldc + n0 + cu * 8) = d;
      }
    }
  } else {
    #pragma unroll
    for (int m = 0; m < 4; ++m) {
      #pragma unroll
      for (int r = 0; r < 4; ++r) {
        const int gm = m0 + wr + m * 16 + row4 + r;
        const bool ok = (mMask >= 0) ? ((gm & mMask) < Mvalid) : (gm < Mvalid);
        #pragma unroll
        for (int n = 0; n < 4; ++n) {
          const int gn = n0 + wc + n * 16 + coln;
          float v = acc[m][n][r] * scale;
          if (RELU) v = fmaxf(v, 0.f);
          if (ok) {
            if (CMODE == 0) Cf[(size_t)gm * ldc + gn] = v;
            else            atomicAdd(&Cf[(size_t)gm * ldc + gn], v);
          }
        }
      }
    }
  }
}

// ---------------- weights: dst[Mp,Kp] bf16 = W^T (+ bias slot at k==Kv) ----
__global__ __launch_bounds__(256) void wt_conv(
    const float* __restrict__ W, const float* __restrict__ bias,
    ushort_t* __restrict__ dst, int Mtot, int ldw, int Kv, int Kp,
    int PADH, int VALH)
{
  const int m = blockIdx.x;
  const int h = m / PADH, c0 = m % PADH;
  const int fout = h * VALH + c0;
  const bool valid = (c0 < VALH) && (fout < Mtot);
  for (int k = threadIdx.x; k < Kp; k += blockDim.x) {
    float v = 0.f;
    if (valid) {
      if (k < Kv) v = W[(size_t)k * ldw + fout];
      else if (k == Kv) v = bias[fout];
    }
    dst[(size_t)m * Kp + k] = f2bf(v);
  }
}

// ---------------- transpose fp32 [Kv,4096] -> bf16 [4096,Kp], bias slot ----
__global__ __launch_bounds__(256) void trans_pad(
    const float* __restrict__ src, ushort_t* __restrict__ dst, int Kv, int Kp)
{
  __shared__ float tl[64][65];
  const int t = threadIdx.x;
  const int f0 = blockIdx.x * 64;
  const int i0 = blockIdx.y * 64;
  const int c = t & 63, rbase = t >> 6;
  #pragma unroll
  for (int it = 0; it < 16; ++it) {
    int r = rbase + it * 4;
    int f = f0 + r;
    tl[r][c] = (f < Kv) ? src[(size_t)f * 4096 + i0 + c] : 0.f;
  }
  __syncthreads();
  #pragma unroll
  for (int it = 0; it < 16; ++it) {
    int r = rbase + it * 4;
    int f = f0 + c;
    if (f < Kp) {
      float v = (f < Kv) ? tl[c][r] : ((f == Kv) ? 1.f : 0.f);
      dst[(size_t)(i0 + r) * Kp + f] = f2bf(v);
    }
  }
}

// ---------------- GraphNorm layer 1: x = skip + attn/r, gn, f32 out --------
__global__ __launch_bounds__(256) void graph_norm_attn1(
    const float* __restrict__ skip, const float* __restrict__ attn,
    const float* __restrict__ r1, float* __restrict__ out,
    const float* __restrict__ w, const float* __restrict__ b,
    const float* __restrict__ ms)
{
  __shared__ float red[4];
  const int t = threadIdx.x;
  const int row = blockIdx.x;            // 0..199
  const int pr = (row / 50) * 128 + row % 50;
  const float* sk = skip + (size_t)pr * 4096;
  const float* at = attn + (size_t)pr * 4096;
  const float* rr = r1 + (size_t)(row / 50) * 4096;
  float v[16];
  float s = 0.f;
  #pragma unroll
  for (int e = 0; e < 4; ++e) {
    const int idx = t * 4 + 1024 * e;
    float4 a = *(const float4*)&sk[idx];
    float4 o = *(const float4*)&at[idx];
    float4 rv = *(const float4*)&rr[idx];
    v[e*4+0] = a.x + o.x / rv.x; v[e*4+1] = a.y + o.y / rv.y;
    v[e*4+2] = a.z + o.z / rv.z; v[e*4+3] = a.w + o.w / rv.w;
    s += v[e*4+0] + v[e*4+1] + v[e*4+2] + v[e*4+3];
  }
  const float mean = block_sum256(s, red) * (1.f / 4096.f);
  const float sub = mean * ms[row];
  float s2 = 0.f;
  #pragma unroll
  for (int e = 0; e < 16; ++e) { v[e] -= sub; s2 += v[e] * v[e]; }
  const float var = block_sum256(s2, red) * (1.f / 4096.f);
  const float scl = rsqrtf(var + 1e-5f) * w[row];
  const float bb = b[row];
  float* y = out + (size_t)row * 4096;
  #pragma unroll
  for (int e = 0; e < 4; ++e) {
    float o0[4];
    #pragma unroll
    for (int q = 0; q < 4; ++q) o0[q] = v[e * 4 + q] * scl + bb;
    *(float4*)&y[t * 4 + 1024 * e] = *(float4*)&o0[0];
  }
}

// ---------------- GraphNorm layer 2: x = skip + (p0+p1)/r, gn, L2, bf16 ----
__global__ __launch_bounds__(256) void graph_norm_attn2(
    const ushort_t* __restrict__ skip, const ushort_t* __restrict__ p2,
    const float* __restrict__ r2, ushort_t* __restrict__ out,
    const float* __restrict__ w, const float* __restrict__ b,
    const float* __restrict__ ms)
{
  __shared__ float red[4];
  const int t = threadIdx.x;
  const int row = blockIdx.x;            // 0..2047
  const ushort_t* sk = skip + (size_t)row * 4096;
  const ushort_t* pa = p2 + (size_t)row * 4096;
  const ushort_t* pb = p2 + (size_t)2048 * 4096 + (size_t)row * 4096;
  const float* rr = r2 + (size_t)(row >> 9) * 4096;
  float v[16];
  float s = 0.f;
  #pragma unroll
  for (int e = 0; e < 4; ++e) {
    const int idx = t * 4 + 1024 * e;
    float a[4], oa[4], ob[4];
    ld4bf(&sk[idx], a); ld4bf(&pa[idx], oa); ld4bf(&pb[idx], ob);
    float4 rv = *(const float4*)&rr[idx];
    v[e*4+0] = a[0] + (oa[0] + ob[0]) / rv.x;
    v[e*4+1] = a[1] + (oa[1] + ob[1]) / rv.y;
    v[e*4+2] = a[2] + (oa[2] + ob[2]) / rv.z;
    v[e*4+3] = a[3] + (oa[3] + ob[3]) / rv.w;
    s += v[e*4+0] + v[e*4+1] + v[e*4+2] + v[e*4+3];
  }
  const float mean = block_sum256(s, red) * (1.f / 4096.f);
  const float sub = mean * ms[row];
  float s2 = 0.f;
  #pragma unroll
  for (int e = 0; e < 16; ++e) { v[e] -= sub; s2 += v[e] * v[e]; }
  const float var = block_sum256(s2, red) * (1.f / 4096.f);
  const float scl = rsqrtf(var + 1e-5f) * w[row];
  const float bb = b[row];
  #pragma unroll
  for (int e = 0; e < 16; ++e) v[e] = v[e] * scl + bb;
  float s3 = 0.f;
  #pragma unroll
  for (int e = 0; e < 16; ++e) s3 += v[e] * v[e];
  const float osc = rsqrtf(block_sum256(s3, red));
  ushort_t* y = out + (size_t)row * 4096;
  #pragma unroll
  for (int e = 0; e < 4; ++e) {
    ushort_t o0[4];
    #pragma unroll
    for (int q = 0; q < 4; ++q) o0[q] = f2bf(v[e * 4 + q] * osc);
    *(ushort2*)&y[t * 4 + 1024 * e] = *(ushort2*)&o0[0];
    *(ushort2*)&y[t * 4 + 1024 * e + 2] = *(ushort2*)&o0[2];
  }
}

// ---------------- out = relu(g0+g1+g2+g3), float4-wide ---------------------
__global__ __launch_bounds__(256) void add4_relu(
    const float* __restrict__ g, float* __restrict__ out)
{
  const size_t i = (size_t)blockIdx.x * 256 + threadIdx.x;
  const size_t ss = (size_t)2048 * 2048 / 4;
  float4 a = ((const float4*)g)[i];
  float4 b = ((const float4*)g)[i + ss];
  float4 c = ((const float4*)g)[i + 2 * ss];
  float4 d = ((const float4*)g)[i + 3 * ss];
  float4 o;
  o.x = fmaxf(a.x + b.x + c.x + d.x, 0.f);
  o.y = fmaxf(a.y + b.y + c.y + d.y, 0.f);
  o.z = fmaxf(a.z + b.z + c.z + d.z, 0.f);
  o.w = fmaxf(a.w + b.w + c.w + d.w, 0.f);
  ((float4*)out)[i] = o;
}

extern "C" void kernel_launch(void* const* d_in, const int* in_sizes, int n_in,
                              void* d_out, int out_size, void* d_ws, size_t ws_size,
                              hipStream_t stream)
{
  (void)in_sizes; (void)n_in; (void)out_size; (void)ws_size;
  const float* lr_x = (const float*)d_in[0];
  const float* Wq1 = (const float*)d_in[1];  const float* bq1 = (const float*)d_in[2];
  const float* Wk1 = (const float*)d_in[3];  const float* bk1 = (const float*)d_in[4];
  const float* Wv1 = (const float*)d_in[5];  const float* bv1 = (const float*)d_in[6];
  const float* Ws1 = (const float*)d_in[7];  const float* bs1 = (const float*)d_in[8];
  const float* gn1w = (const float*)d_in[9]; const float* gn1b = (const float*)d_in[10];
  const float* gn1ms = (const float*)d_in[11];
  const float* Wq2 = (const float*)d_in[12]; const float* bq2 = (const float*)d_in[13];
  const float* Wk2 = (const float*)d_in[14]; const float* bk2 = (const float*)d_in[15];
  const float* Wv2 = (const float*)d_in[16]; const float* bv2 = (const float*)d_in[17];
  const float* Ws2 = (const float*)d_in[18]; const float* bs2 = (const float*)d_in[19];
  const float* gn2w = (const float*)d_in[20]; const float* gn2b = (const float*)d_in[21];
  const float* gn2ms = (const float*)d_in[22];

  // ---- workspace carve with explicit aliasing (~242.3 MB total) ----
  char* p = (char*)d_ws;
  auto alloc = [&](size_t bytes) { char* r = p; p += (bytes + 255) & ~(size_t)255; return r; };
  const size_t PSTR = (size_t)4096 * 4096;
  ushort_t* Pall = (ushort_t*)alloc(PSTR * 4 * 2);              // 134.2 MB; Gram partials alias
  ushort_t* xb   = (ushort_t*)alloc((size_t)4096 * 544 * 2);
  ushort_t* qk1b = (ushort_t*)alloc((size_t)4096 * 512 * 2);
  ushort_t* v1b  = (ushort_t*)alloc((size_t)512 * 4096 * 2);
  char*     u0   = alloc((size_t)16 * 1024 * 1024);             // s1p+o1p, later h2b
  float*    s1p  = (float*)u0;                                  // [512,4096] f32 skip
  float*    o1p  = (float*)(u0 + (size_t)8 * 1024 * 1024);      // [512,4096] f32 attn accum
  float*    h1nT = (float*)   alloc((size_t)200 * 4096 * 4);
  ushort_t* h1nb = (ushort_t*)alloc((size_t)4096 * 256 * 2);
  ushort_t* Wqk1 = (ushort_t*)alloc((size_t)512 * 544 * 2);
  ushort_t* Wv1b = (ushort_t*)alloc((size_t)512 * 544 * 2);
  ushort_t* Ws1p = (ushort_t*)alloc((size_t)512 * 544 * 2);
  ushort_t* Wqk2 = (ushort_t*)alloc((size_t)4096 * 256 * 2);
  ushort_t* Wcat = (ushort_t*)alloc((size_t)4096 * 256 * 2);    // [v2 | s2] weights
  ushort_t* qk2b = (ushort_t*)alloc((size_t)4096 * 4096 * 2);   // [node, 2048q|2048k]
  ushort_t* vs2b = (ushort_t*)alloc((size_t)4096 * 4096 * 2);   // rows 0..2047=v2T, 2048..4095=skip2
  float*    r1   = (float*)   alloc((size_t)4 * 4096 * 4);
  float*    r2   = (float*)   alloc((size_t)4 * 4096 * 4);
  // aliases (regions dead by the time the alias is written):
  ushort_t* p2   = qk2b;           // PV-2 partials: qk2b dead after scores-2
  ushort_t* h2b  = (ushort_t*)u0;  // gn2 output: s1p/o1p dead after gn1
  float*    g4   = (float*)Pall;   // Gram partials: Pall dead after PV-2

  const dim3 b256(256, 1, 1);
  const dim3 b512(512, 1, 1);
  const float sc1 = 0.14142135623730951f;  // 1/sqrt(50)
  const float sc2 = 0.04419417382415922f;  // 1/sqrt(512)

  hipMemsetAsync(r1, 0, (size_t)4 * 4096 * 4, stream);
  hipMemsetAsync(r2, 0, (size_t)4 * 4096 * 4, stream);
  hipMemsetAsync(o1p, 0, (size_t)512 * 4096 * 4, stream);

  // ---- weight conversions
  wt_conv<<<dim3(256),  b256, 0, stream>>>(Wq1, bq1, Wqk1,             200, 200, 512, 544, 64, 50);
  wt_conv<<<dim3(256),  b256, 0, stream>>>(Wk1, bk1, Wqk1 + 256 * 544, 200, 200, 512, 544, 64, 50);
  wt_conv<<<dim3(512),  b256, 0, stream>>>(Wv1, bv1, Wv1b,             200, 200, 512, 544, 128, 50);
  wt_conv<<<dim3(512),  b256, 0, stream>>>(Ws1, bs1, Ws1p,             200, 200, 512, 544, 128, 50);
  wt_conv<<<dim3(2048), b256, 0, stream>>>(Wq2, bq2, Wqk2,              2048, 2048, 200, 256, 2048, 2048);
  wt_conv<<<dim3(2048), b256, 0, stream>>>(Wk2, bk2, Wqk2 + 2048 * 256, 2048, 2048, 200, 256, 2048, 2048);
  wt_conv<<<dim3(2048), b256, 0, stream>>>(Wv2, bv2, Wcat,              2048, 2048, 200, 256, 2048, 2048);
  wt_conv<<<dim3(2048), b256, 0, stream>>>(Ws2, bs2, Wcat + 2048 * 256, 2048, 2048, 200, 256, 2048, 2048);
  trans_pad<<<dim3(9, 64), b256, 0, stream>>>(lr_x, xb, 512, 544);

  // ---- layer-1 projections
  mfma_bt<1, false, false><<<dim3(4, 32), b256, 0, stream>>>(
      xb, Wqk1, qk1b, 544, 544, 512, 544, 1, 0, 0, 0, -1, 0, -1, 4096, 1.f, nullptr);
  mfma_bt<1, false, false><<<dim3(32, 4), b256, 0, stream>>>(
      Wv1b, xb, v1b, 544, 544, 4096, 544, 1, 0, 0, 0, -1, 0, -1, 512, 1.f, nullptr);
  mfma_bt<0, false, false><<<dim3(32, 4), b256, 0, stream>>>(
      Ws1p, xb, s1p, 544, 544, 4096, 544, 1, 0, 0, 0, -1, 0, 127, 50, 1.f, nullptr);

  // ---- attention 1: expS scores (+rowsum) -> PV atomic -> gn1
  mfma_bt<1, false, true><<<dim3(32, 32, 4), b256, 0, stream>>>(
      qk1b, qk1b + 256, Pall, 512, 512, 4096, 64, 1,
      64, 64, PSTR, -1, 0, -1, 4096, sc1, r1);
  mfma_bt<2, false, false><<<dim3(32, 4, 8), b256, 0, stream>>>(
      v1b, Pall, o1p, 4096, 4096, 4096, 4096, 8,
      0, 0, 0, 7, PSTR, 127, 50, 1.f, nullptr);
  graph_norm_attn1<<<dim3(200), b256, 0, stream>>>(s1p, o1p, r1, h1nT, gn1w, gn1b, gn1ms);
  trans_pad<<<dim3(4, 64), b256, 0, stream>>>(h1nT, h1nb, 200, 256);

  // ---- layer-2 projections (8-phase): qk node-major; [v|skip] feature-major
  mfma256_8ph<1, false, false><<<dim3(16, 16), b512, 0, stream>>>(
      h1nb, Wqk2, qk2b, 256, 256, 4096, 256, 1, 0, 0, 0, -1, 0, 4096, 1.f, nullptr);
  mfma256_8ph<1, false, false><<<dim3(16, 16), b512, 0, stream>>>(
      Wcat, h1nb, vs2b, 256, 256, 4096, 256, 1, 0, 0, 0, -1, 0, 4096, 1.f, nullptr);

  // ---- attention 2: expS scores (+rowsum) -> PV partials (alias qk2b) -> gn2
  mfma256_8ph<1, false, true><<<dim3(16, 16, 4), b512, 0, stream>>>(
      qk2b, qk2b + 2048, Pall, 4096, 4096, 4096, 512, 1,
      512, 512, PSTR, -1, 0, 4096, sc2, r2);
  mfma256_8ph<1, false, false><<<dim3(16, 8, 2), b512, 0, stream>>>(
      vs2b, Pall, p2, 4096, 4096, 4096, 4096, 2,
      0, 0, (size_t)2048 * 4096, 9, PSTR, 2048, 1.f, nullptr);
  graph_norm_attn2<<<dim3(2048), b256, 0, stream>>>(
      vs2b + (size_t)2048 * 4096, p2, r2, h2b, gn2w, gn2b, gn2ms);

  // ---- out = relu(h2n . h2n^T): K-split partials (alias Pall) + reduce
  mfma256_8ph<0, false, false><<<dim3(8, 8, 4), b512, 0, stream>>>(
      h2b, h2b, g4, 4096, 4096, 2048, 4096, 4,
      0, 0, (size_t)2048 * 2048, -1, 0, 2048, 1.f, nullptr);
  add4_relu<<<dim3(4096), b256, 0, stream>>>(g4, (float*)d_out);
}

// Round 8
// 522.949 us; speedup vs baseline: 1.0168x; 1.0168x over previous
//
#include <hip/hip_runtime.h>
#include <math.h>

typedef unsigned int u32;
typedef unsigned short ushort_t;
typedef __attribute__((ext_vector_type(8))) short short8;
typedef __attribute__((ext_vector_type(4))) float f32x4;

__device__ __forceinline__ ushort_t f2bf(float x) {
  u32 u = __float_as_uint(x);
  u32 r = (u + 0x7fffu + ((u >> 16) & 1u)) >> 16;
  return (ushort_t)r;
}
__device__ __forceinline__ float bf2f(u32 s) {
  return __uint_as_float(s << 16);
}
__device__ __forceinline__ void ld4bf(const ushort_t* p, float* o) {
  uint2 u = *(const uint2*)p;
  o[0] = bf2f(u.x & 0xffffu); o[1] = bf2f(u.x >> 16);
  o[2] = bf2f(u.y & 0xffffu); o[3] = bf2f(u.y >> 16);
}

// ---------------- block reduction helpers (256 threads = 4 waves) ----------
__device__ __forceinline__ float block_sum256(float v, float* red) {
  #pragma unroll
  for (int o = 32; o > 0; o >>= 1) v += __shfl_down(v, o, 64);
  __syncthreads();
  if ((threadIdx.x & 63) == 0) red[threadIdx.x >> 6] = v;
  __syncthreads();
  return red[0] + red[1] + red[2] + red[3];
}

// =====================================================================
// 256x256-tile, 8-phase, counted-vmcnt MFMA GEMM (m201-style schedule).
// Use for LONG-K dispatches only (128 KiB LDS -> 1 block/CU; prologue and
// epilogue are exposed, so short K regresses here — R7 lesson).
// C[m,n] (op)= scale * sum_k A[m,k]*B[n,k];  A:[M,K] bf16, B:[N,K] bf16.
// BK=64, K/zsplit % 128 == 0. 512 thr = 8 waves (2M x 4N).
// zsplit>1: grid.z = K-split, C += z*zC. zsplit==1: grid.z = batch (zA/zB/zC).
// bShift>=0: B += (m0>>bShift)*bHead (per-m-tile head select).
// CMODE: 0 = store f32 (+RELU), 1 = store bf16, 2 = atomicAdd f32.
// EXPSUM: v=exp(v*scale) before store; row-sums atomic into Rs[z*4096+gm].
// =====================================================================
#define RD_A(bb, mm, cc) (*(const short8*)(lsAc + (bb)*32768 + arow + (mm)*2048 + (cc)))
#define RD_B(bb, nn, cc) (*(const short8*)(lsBc + (bb)*32768 + brow + (nn)*2048 + (cc)))

#define MM8(nn, bv) { \
  acc[0][nn] = __builtin_amdgcn_mfma_f32_16x16x32_bf16(a0, bv, acc[0][nn], 0,0,0); \
  acc[1][nn] = __builtin_amdgcn_mfma_f32_16x16x32_bf16(a1, bv, acc[1][nn], 0,0,0); \
  acc[2][nn] = __builtin_amdgcn_mfma_f32_16x16x32_bf16(a2, bv, acc[2][nn], 0,0,0); \
  acc[3][nn] = __builtin_amdgcn_mfma_f32_16x16x32_bf16(a3, bv, acc[3][nn], 0,0,0); \
  acc[4][nn] = __builtin_amdgcn_mfma_f32_16x16x32_bf16(a4, bv, acc[4][nn], 0,0,0); \
  acc[5][nn] = __builtin_amdgcn_mfma_f32_16x16x32_bf16(a5, bv, acc[5][nn], 0,0,0); \
  acc[6][nn] = __builtin_amdgcn_mfma_f32_16x16x32_bf16(a6, bv, acc[6][nn], 0,0,0); \
  acc[7][nn] = __builtin_amdgcn_mfma_f32_16x16x32_bf16(a7, bv, acc[7][nn], 0,0,0); }

#define STG(BASE, LD, LS, bb, hf, tt) { \
  _Pragma("unroll") \
  for (int ii = 0; ii < 2; ++ii) { \
    const int s_ = t + ii * 512; \
    const int r_ = s_ >> 3; \
    const int lc_ = (s_ & 7) ^ (r_ & 7); \
    __builtin_amdgcn_global_load_lds( \
      (const __attribute__((address_space(1))) u32*)((BASE) + (size_t)((hf) * 128 + r_) * (LD) + (size_t)(tt) * 64 + lc_ * 8), \
      (__attribute__((address_space(3))) u32*)(&(LS)[bb][(hf) * 8192 + s_ * 8]), 16, 0, 0); \
  } }

#define BAR() __builtin_amdgcn_s_barrier()
#define PRIO(x) __builtin_amdgcn_s_setprio(x)

#define GRP(bf, tS1, tS2) { \
  a0=RD_A(bf,0,c0); a1=RD_A(bf,1,c0); a2=RD_A(bf,2,c0); a3=RD_A(bf,3,c0); \
  a4=RD_A(bf,4,c0); a5=RD_A(bf,5,c0); a6=RD_A(bf,6,c0); a7=RD_A(bf,7,c0); \
  b0=RD_B(bf,0,c0); b1=RD_B(bf,1,c0); \
  STG(Ab, lda, lsA, 1-(bf), 1, tS1); STG(Bb, ldb, lsB, 1-(bf), 0, tS1); \
  BAR(); PRIO(1); MM8(0, b0); MM8(1, b1); PRIO(0); BAR(); \
  b2=RD_B(bf,2,c0); b3=RD_B(bf,3,c0); \
  STG(Bb, ldb, lsB, 1-(bf), 1, tS1); \
  BAR(); PRIO(1); MM8(2, b2); MM8(3, b3); PRIO(0); BAR(); \
  a0=RD_A(bf,0,c1); a1=RD_A(bf,1,c1); a2=RD_A(bf,2,c1); a3=RD_A(bf,3,c1); \
  a4=RD_A(bf,4,c1); a5=RD_A(bf,5,c1); a6=RD_A(bf,6,c1); a7=RD_A(bf,7,c1); \
  b0=RD_B(bf,0,c1); b1=RD_B(bf,1,c1); \
  BAR(); PRIO(1); MM8(0, b0); MM8(1, b1); PRIO(0); BAR(); \
  b2=RD_B(bf,2,c1); b3=RD_B(bf,3,c1); \
  STG(Ab, lda, lsA, (bf), 0, tS2); \
  BAR(); PRIO(1); MM8(2, b2); MM8(3, b3); PRIO(0); \
  asm volatile("s_waitcnt vmcnt(2)" ::: "memory"); \
  BAR(); }

template<int CMODE, bool RELU, bool EXPSUM>
__global__ __launch_bounds__(512, 2) void mfma256_8ph(
    const ushort_t* __restrict__ A, const ushort_t* __restrict__ B,
    void* __restrict__ Cv, int lda, int ldb, int ldc,
    int K, int zsplit, size_t zA, size_t zB, size_t zC,
    int bShift, size_t bHead, int Mvalid, float scale,
    float* __restrict__ Rs)
{
  __shared__ ushort_t lsA[2][16384];
  __shared__ ushort_t lsB[2][16384];
  const int t = threadIdx.x;
  const int gx = gridDim.x;
  const int nwg = gx * gridDim.y;
  const int bid = blockIdx.y * gx + blockIdx.x;
  const int qq = nwg >> 3, rr_ = nwg & 7;
  const int xcd = bid & 7, idx = bid >> 3;
  const int swz = (xcd < rr_ ? xcd * (qq + 1) : rr_ * (qq + 1) + (xcd - rr_) * qq) + idx;
  const int m0 = (swz / gx) * 256;
  const int n0 = (swz % gx) * 256;
  const int z = blockIdx.z;
  int Kc = K, kOff = 0;
  size_t aZ = 0, bZ = 0, cZ = 0;
  if (zsplit > 1) { Kc = K / zsplit; kOff = z * Kc; cZ = (size_t)z * zC; }
  else { aZ = (size_t)z * zA; bZ = (size_t)z * zB; cZ = (size_t)z * zC; }
  const ushort_t* Ab = A + aZ + (size_t)m0 * lda + kOff;
  const ushort_t* Bb = B + bZ + (size_t)n0 * ldb + kOff
                     + (bShift >= 0 ? (size_t)(m0 >> bShift) * bHead : 0);
  const int NT = Kc / 64;

  f32x4 acc[8][4];
  #pragma unroll
  for (int i = 0; i < 8; ++i)
    #pragma unroll
    for (int j = 0; j < 4; ++j) acc[i][j] = (f32x4){0.f, 0.f, 0.f, 0.f};

  const int lane = t & 63;
  const int wv = t >> 6;
  const int wr = (wv >> 2) * 128;
  const int wc = (wv & 3) * 64;
  const int lr = lane & 15;
  const int kc = lane >> 4;
  const int sw = lane & 7;
  const int c0 = (kc ^ sw) * 16;
  const int c1 = c0 ^ 64;
  const int arow = (wr + lr) * 128;
  const int brow = (wc + lr) * 128;
  const char* lsAc = (const char*)lsA;
  const char* lsBc = (const char*)lsB;

  short8 a0, a1, a2, a3, a4, a5, a6, a7, b0, b1, b2, b3;

  STG(Ab, lda, lsA, 0, 0, 0); STG(Ab, lda, lsA, 0, 1, 0);
  STG(Bb, ldb, lsB, 0, 0, 0); STG(Bb, ldb, lsB, 0, 1, 0);
  STG(Ab, lda, lsA, 1, 0, 1);
  asm volatile("s_waitcnt vmcnt(2)" ::: "memory");
  BAR();

  const int NITER = NT >> 1;
  for (int it = 0; it < NITER; ++it) {
    const int tb = 2 * it;
    const int s1 = tb + 1;
    const int s2 = (tb + 2 < NT) ? tb + 2 : 0;
    const int s3 = (tb + 3 < NT) ? tb + 3 : 0;
    GRP(0, s1, s2)
    GRP(1, s2, s3)
  }

  const int row4 = (lane >> 4) * 4;
  const int coln = lane & 15;
  float* Cf = (float*)Cv + cZ;
  ushort_t* Ch = (ushort_t*)Cv + cZ;
  float* rs = EXPSUM ? (Rs + (size_t)z * 4096) : nullptr;
  #pragma unroll
  for (int m = 0; m < 8; ++m) {
    #pragma unroll
    for (int r = 0; r < 4; ++r) {
      const int gm = m0 + wr + m * 16 + row4 + r;
      const bool ok = gm < Mvalid;
      float rowpart = 0.f;
      #pragma unroll
      for (int n = 0; n < 4; ++n) {
        const int gn = n0 + wc + n * 16 + coln;
        float v = acc[m][n][r] * scale;
        if (EXPSUM) { v = __expf(v); rowpart += v; }
        if (RELU) v = fmaxf(v, 0.f);
        if (ok) {
          if (CMODE == 0)      Cf[(size_t)gm * ldc + gn] = v;
          else if (CMODE == 1) Ch[(size_t)gm * ldc + gn] = f2bf(v);
          else                 atomicAdd(&Cf[(size_t)gm * ldc + gn], v);
        }
      }
      if (EXPSUM) {
        rowpart += __shfl_xor(rowpart, 1);
        rowpart += __shfl_xor(rowpart, 2);
        rowpart += __shfl_xor(rowpart, 4);
        rowpart += __shfl_xor(rowpart, 8);
        if (ok && (lane & 15) == 0) atomicAdd(&rs[gm], rowpart);
      }
    }
  }
}

#undef GRP
#undef STG
#undef MM8
#undef RD_A
#undef RD_B

// ================= 128x128-tile MFMA GEMM, 256 threads =====================
// 32 KiB LDS -> ~5 blocks/CU: use for SHORT-K dispatches where co-resident
// blocks hide prologue/epilogue latency (R7 lesson).
template<int CMODE, bool RELU, bool EXPSUM>
__global__ __launch_bounds__(256) void mfma_bt(
    const ushort_t* __restrict__ A, const ushort_t* __restrict__ B,
    void* __restrict__ Cv, int lda, int ldb, int ldc,
    int K, int Ksplit, size_t zA, size_t zB, size_t zC,
    int bShift, size_t bHead, int mMask, int Mvalid, float scale,
    float* __restrict__ Rs)
{
  __shared__ ushort_t lsA[2][128 * 32];
  __shared__ ushort_t lsB[2][128 * 32];
  const int t  = threadIdx.x;
  const int m0 = blockIdx.y * 128;
  const int n0 = blockIdx.x * 128;
  const int z = blockIdx.z;
  int Kc = K, kOff = 0;
  size_t aZ = 0, bZ = 0, cZ = 0;
  if (Ksplit > 1) { Kc = K / Ksplit; kOff = z * Kc; cZ = (size_t)z * zC; }
  else { aZ = (size_t)z * zA; bZ = (size_t)z * zB; cZ = (size_t)z * zC; }
  const int NT = Kc / 32;
  const ushort_t* Ab = A + aZ + (size_t)m0 * lda + kOff;
  const ushort_t* Bb = B + bZ + (size_t)n0 * ldb + kOff
                     + (bShift >= 0 ? (size_t)(m0 >> bShift) * bHead : 0);
  const int cs = t & 3;

  f32x4 acc[4][4];
  #pragma unroll
  for (int i = 0; i < 4; ++i)
    #pragma unroll
    for (int j = 0; j < 4; ++j) acc[i][j] = (f32x4){0.f, 0.f, 0.f, 0.f};

  const int lane = t & 63;
  const int wv = t >> 6;
  const int wr = (wv >> 1) * 64;
  const int wc = (wv & 1) * 64;
  const int lr = lane & 15;
  const int kc = lane >> 4;

  int roffA[4], roffB[4];
  #pragma unroll
  for (int m = 0; m < 4; ++m) {
    int ra = wr + m * 16 + lr;
    roffA[m] = ra * 64 + ((kc ^ (ra & 3)) * 16);
    int rb = wc + m * 16 + lr;
    roffB[m] = rb * 64 + ((kc ^ (rb & 3)) * 16);
  }

  auto stage = [&](int buf, int kt) {
    const ushort_t* As = Ab + kt * 32;
    const ushort_t* Bs = Bb + kt * 32;
    #pragma unroll
    for (int i = 0; i < 2; ++i) {
      int s = t + i * 256;
      int r = s >> 2;
      int c = cs ^ (r & 3);
      __builtin_amdgcn_global_load_lds(
          (const __attribute__((address_space(1))) u32*)(As + (size_t)r * lda + c * 8),
          (__attribute__((address_space(3))) u32*)(&lsA[buf][s * 8]), 16, 0, 0);
    }
    #pragma unroll
    for (int i = 0; i < 2; ++i) {
      int s = t + i * 256;
      int r = s >> 2;
      int c = cs ^ (r & 3);
      __builtin_amdgcn_global_load_lds(
          (const __attribute__((address_space(1))) u32*)(Bs + (size_t)r * ldb + c * 8),
          (__attribute__((address_space(3))) u32*)(&lsB[buf][s * 8]), 16, 0, 0);
    }
  };

  stage(0, 0);
  __syncthreads();
  int cur = 0;
  for (int kt = 0; kt < NT; ++kt) {
    if (kt + 1 < NT) stage(cur ^ 1, kt + 1);
    short8 af[4], bfr[4];
    const char* baseA = (const char*)&lsA[cur][0];
    const char* baseB = (const char*)&lsB[cur][0];
    #pragma unroll
    for (int m = 0; m < 4; ++m) af[m]  = *(const short8*)(baseA + roffA[m]);
    #pragma unroll
    for (int n = 0; n < 4; ++n) bfr[n] = *(const short8*)(baseB + roffB[n]);
    #pragma unroll
    for (int m = 0; m < 4; ++m)
      #pragma unroll
      for (int n = 0; n < 4; ++n)
        acc[m][n] = __builtin_amdgcn_mfma_f32_16x16x32_bf16(af[m], bfr[n], acc[m][n], 0, 0, 0);
    __syncthreads();
    cur ^= 1;
  }

  const int row4 = (lane >> 4) * 4;
  const int coln = lane & 15;
  float* Cf = (float*)Cv + cZ;
  ushort_t* Ch = (ushort_t*)Cv + cZ;
  float* rs = EXPSUM ? (Rs + (size_t)z * 4096) : nullptr;
  #pragma unroll
  for (int m = 0; m < 4; ++m) {
    #pragma unroll
    for (int r = 0; r < 4; ++r) {
      const int gm = m0 + wr + m * 16 + row4 + r;
      const bool ok = (mMask >= 0) ? ((gm & mMask) < Mvalid) : (gm < Mvalid);
      float rowpart = 0.f;
      #pragma unroll
      for (int n = 0; n < 4; ++n) {
        const int gn = n0 + wc + n * 16 + coln;
        float v = acc[m][n][r] * scale;
        if (EXPSUM) { v = __expf(v); rowpart += v; }
        if (RELU) v = fmaxf(v, 0.f);
        if (ok) {
          if (CMODE == 0)      Cf[(size_t)gm * ldc + gn] = v;
          else if (CMODE == 1) Ch[(size_t)gm * ldc + gn] = f2bf(v);
          else                 atomicAdd(&Cf[(size_t)gm * ldc + gn], v);
        }
      }
      if (EXPSUM) {
        rowpart += __shfl_xor(rowpart, 1);
        rowpart += __shfl_xor(rowpart, 2);
        rowpart += __shfl_xor(rowpart, 4);
        rowpart += __shfl_xor(rowpart, 8);
        if (ok && (lane & 15) == 0) atomicAdd(&rs[gm], rowpart);
      }
    }
  }
}

// ---------------- weights: dst[Mp,Kp] bf16 = W^T (+ bias slot at k==Kv) ----
__global__ __launch_bounds__(256) void wt_conv(
    const float* __restrict__ W, const float* __restrict__ bias,
    ushort_t* __restrict__ dst, int Mtot, int ldw, int Kv, int Kp,
    int PADH, int VALH)
{
  const int m = blockIdx.x;
  const int h = m / PADH, c0 = m % PADH;
  const int fout = h * VALH + c0;
  const bool valid = (c0 < VALH) && (fout < Mtot);
  for (int k = threadIdx.x; k < Kp; k += blockDim.x) {
    float v = 0.f;
    if (valid) {
      if (k < Kv) v = W[(size_t)k * ldw + fout];
      else if (k == Kv) v = bias[fout];
    }
    dst[(size_t)m * Kp + k] = f2bf(v);
  }
}

// ---------------- transpose fp32 [Kv,4096] -> bf16 [4096,Kp], bias slot ----
__global__ __launch_bounds__(256) void trans_pad(
    const float* __restrict__ src, ushort_t* __restrict__ dst, int Kv, int Kp)
{
  __shared__ float tl[64][65];
  const int t = threadIdx.x;
  const int f0 = blockIdx.x * 64;
  const int i0 = blockIdx.y * 64;
  const int c = t & 63, rbase = t >> 6;
  #pragma unroll
  for (int it = 0; it < 16; ++it) {
    int r = rbase + it * 4;
    int f = f0 + r;
    tl[r][c] = (f < Kv) ? src[(size_t)f * 4096 + i0 + c] : 0.f;
  }
  __syncthreads();
  #pragma unroll
  for (int it = 0; it < 16; ++it) {
    int r = rbase + it * 4;
    int f = f0 + c;
    if (f < Kp) {
      float v = (f < Kv) ? tl[c][r] : ((f == Kv) ? 1.f : 0.f);
      dst[(size_t)(i0 + r) * Kp + f] = f2bf(v);
    }
  }
}

// ---------------- GraphNorm layer 1: x = skip + attn/r, gn, f32 out --------
__global__ __launch_bounds__(256) void graph_norm_attn1(
    const float* __restrict__ skip, const float* __restrict__ attn,
    const float* __restrict__ r1, float* __restrict__ out,
    const float* __restrict__ w, const float* __restrict__ b,
    const float* __restrict__ ms)
{
  __shared__ float red[4];
  const int t = threadIdx.x;
  const int row = blockIdx.x;            // 0..199
  const int pr = (row / 50) * 128 + row % 50;
  const float* sk = skip + (size_t)pr * 4096;
  const float* at = attn + (size_t)pr * 4096;
  const float* rr = r1 + (size_t)(row / 50) * 4096;
  float v[16];
  float s = 0.f;
  #pragma unroll
  for (int e = 0; e < 4; ++e) {
    const int idx = t * 4 + 1024 * e;
    float4 a = *(const float4*)&sk[idx];
    float4 o = *(const float4*)&at[idx];
    float4 rv = *(const float4*)&rr[idx];
    v[e*4+0] = a.x + o.x / rv.x; v[e*4+1] = a.y + o.y / rv.y;
    v[e*4+2] = a.z + o.z / rv.z; v[e*4+3] = a.w + o.w / rv.w;
    s += v[e*4+0] + v[e*4+1] + v[e*4+2] + v[e*4+3];
  }
  const float mean = block_sum256(s, red) * (1.f / 4096.f);
  const float sub = mean * ms[row];
  float s2 = 0.f;
  #pragma unroll
  for (int e = 0; e < 16; ++e) { v[e] -= sub; s2 += v[e] * v[e]; }
  const float var = block_sum256(s2, red) * (1.f / 4096.f);
  const float scl = rsqrtf(var + 1e-5f) * w[row];
  const float bb = b[row];
  float* y = out + (size_t)row * 4096;
  #pragma unroll
  for (int e = 0; e < 4; ++e) {
    float o0[4];
    #pragma unroll
    for (int q = 0; q < 4; ++q) o0[q] = v[e * 4 + q] * scl + bb;
    *(float4*)&y[t * 4 + 1024 * e] = *(float4*)&o0[0];
  }
}

// ---------------- GraphNorm layer 2: x = skip + (p0+p1)/r, gn, L2, bf16 ----
__global__ __launch_bounds__(256) void graph_norm_attn2(
    const ushort_t* __restrict__ skip, const ushort_t* __restrict__ p2,
    const float* __restrict__ r2, ushort_t* __restrict__ out,
    const float* __restrict__ w, const float* __restrict__ b,
    const float* __restrict__ ms)
{
  __shared__ float red[4];
  const int t = threadIdx.x;
  const int row = blockIdx.x;            // 0..2047
  const ushort_t* sk = skip + (size_t)row * 4096;
  const ushort_t* pa = p2 + (size_t)row * 4096;
  const ushort_t* pb = p2 + (size_t)2048 * 4096 + (size_t)row * 4096;
  const float* rr = r2 + (size_t)(row >> 9) * 4096;
  float v[16];
  float s = 0.f;
  #pragma unroll
  for (int e = 0; e < 4; ++e) {
    const int idx = t * 4 + 1024 * e;
    float a[4], oa[4], ob[4];
    ld4bf(&sk[idx], a); ld4bf(&pa[idx], oa); ld4bf(&pb[idx], ob);
    float4 rv = *(const float4*)&rr[idx];
    v[e*4+0] = a[0] + (oa[0] + ob[0]) / rv.x;
    v[e*4+1] = a[1] + (oa[1] + ob[1]) / rv.y;
    v[e*4+2] = a[2] + (oa[2] + ob[2]) / rv.z;
    v[e*4+3] = a[3] + (oa[3] + ob[3]) / rv.w;
    s += v[e*4+0] + v[e*4+1] + v[e*4+2] + v[e*4+3];
  }
  const float mean = block_sum256(s, red) * (1.f / 4096.f);
  const float sub = mean * ms[row];
  float s2 = 0.f;
  #pragma unroll
  for (int e = 0; e < 16; ++e) { v[e] -= sub; s2 += v[e] * v[e]; }
  const float var = block_sum256(s2, red) * (1.f / 4096.f);
  const float scl = rsqrtf(var + 1e-5f) * w[row];
  const float bb = b[row];
  #pragma unroll
  for (int e = 0; e < 16; ++e) v[e] = v[e] * scl + bb;
  float s3 = 0.f;
  #pragma unroll
  for (int e = 0; e < 16; ++e) s3 += v[e] * v[e];
  const float osc = rsqrtf(block_sum256(s3, red));
  ushort_t* y = out + (size_t)row * 4096;
  #pragma unroll
  for (int e = 0; e < 4; ++e) {
    ushort_t o0[4];
    #pragma unroll
    for (int q = 0; q < 4; ++q) o0[q] = f2bf(v[e * 4 + q] * osc);
    *(ushort2*)&y[t * 4 + 1024 * e] = *(ushort2*)&o0[0];
    *(ushort2*)&y[t * 4 + 1024 * e + 2] = *(ushort2*)&o0[2];
  }
}

// ---------------- out = relu(g0+g1+g2+g3), float4-wide ---------------------
__global__ __launch_bounds__(256) void add4_relu(
    const float* __restrict__ g, float* __restrict__ out)
{
  const size_t i = (size_t)blockIdx.x * 256 + threadIdx.x;
  const size_t ss = (size_t)2048 * 2048 / 4;
  float4 a = ((const float4*)g)[i];
  float4 b = ((const float4*)g)[i + ss];
  float4 c = ((const float4*)g)[i + 2 * ss];
  float4 d = ((const float4*)g)[i + 3 * ss];
  float4 o;
  o.x = fmaxf(a.x + b.x + c.x + d.x, 0.f);
  o.y = fmaxf(a.y + b.y + c.y + d.y, 0.f);
  o.z = fmaxf(a.z + b.z + c.z + d.z, 0.f);
  o.w = fmaxf(a.w + b.w + c.w + d.w, 0.f);
  ((float4*)out)[i] = o;
}

extern "C" void kernel_launch(void* const* d_in, const int* in_sizes, int n_in,
                              void* d_out, int out_size, void* d_ws, size_t ws_size,
                              hipStream_t stream)
{
  (void)in_sizes; (void)n_in; (void)out_size; (void)ws_size;
  const float* lr_x = (const float*)d_in[0];
  const float* Wq1 = (const float*)d_in[1];  const float* bq1 = (const float*)d_in[2];
  const float* Wk1 = (const float*)d_in[3];  const float* bk1 = (const float*)d_in[4];
  const float* Wv1 = (const float*)d_in[5];  const float* bv1 = (const float*)d_in[6];
  const float* Ws1 = (const float*)d_in[7];  const float* bs1 = (const float*)d_in[8];
  const float* gn1w = (const float*)d_in[9]; const float* gn1b = (const float*)d_in[10];
  const float* gn1ms = (const float*)d_in[11];
  const float* Wq2 = (const float*)d_in[12]; const float* bq2 = (const float*)d_in[13];
  const float* Wk2 = (const float*)d_in[14]; const float* bk2 = (const float*)d_in[15];
  const float* Wv2 = (const float*)d_in[16]; const float* bv2 = (const float*)d_in[17];
  const float* Ws2 = (const float*)d_in[18]; const float* bs2 = (const float*)d_in[19];
  const float* gn2w = (const float*)d_in[20]; const float* gn2b = (const float*)d_in[21];
  const float* gn2ms = (const float*)d_in[22];

  // ---- workspace carve with explicit aliasing (~242.3 MB total) ----
  char* p = (char*)d_ws;
  auto alloc = [&](size_t bytes) { char* r = p; p += (bytes + 255) & ~(size_t)255; return r; };
  const size_t PSTR = (size_t)4096 * 4096;
  ushort_t* Pall = (ushort_t*)alloc(PSTR * 4 * 2);              // 134.2 MB; Gram partials alias
  ushort_t* xb   = (ushort_t*)alloc((size_t)4096 * 544 * 2);
  ushort_t* qk1b = (ushort_t*)alloc((size_t)4096 * 512 * 2);
  ushort_t* v1b  = (ushort_t*)alloc((size_t)512 * 4096 * 2);
  char*     u0   = alloc((size_t)16 * 1024 * 1024);             // s1p+o1p, later h2b
  float*    s1p  = (float*)u0;                                  // [512,4096] f32 skip
  float*    o1p  = (float*)(u0 + (size_t)8 * 1024 * 1024);      // [512,4096] f32 attn accum
  float*    h1nT = (float*)   alloc((size_t)200 * 4096 * 4);
  ushort_t* h1nb = (ushort_t*)alloc((size_t)4096 * 256 * 2);
  ushort_t* Wqk1 = (ushort_t*)alloc((size_t)512 * 544 * 2);
  ushort_t* Wv1b = (ushort_t*)alloc((size_t)512 * 544 * 2);
  ushort_t* Ws1p = (ushort_t*)alloc((size_t)512 * 544 * 2);
  ushort_t* Wqk2 = (ushort_t*)alloc((size_t)4096 * 256 * 2);
  ushort_t* Wcat = (ushort_t*)alloc((size_t)4096 * 256 * 2);    // [v2 | s2] weights
  ushort_t* qk2b = (ushort_t*)alloc((size_t)4096 * 4096 * 2);   // [node, 2048q|2048k]
  ushort_t* vs2b = (ushort_t*)alloc((size_t)4096 * 4096 * 2);   // rows 0..2047=v2T, 2048..4095=skip2
  float*    r1   = (float*)   alloc((size_t)4 * 4096 * 4);
  float*    r2   = (float*)   alloc((size_t)4 * 4096 * 4);
  // aliases (regions dead by the time the alias is written):
  ushort_t* p2   = qk2b;           // PV-2 partials: qk2b dead after scores-2
  ushort_t* h2b  = (ushort_t*)u0;  // gn2 output: s1p/o1p dead after gn1
  float*    g4   = (float*)Pall;   // Gram partials: Pall dead after PV-2

  const dim3 b256(256, 1, 1);
  const dim3 b512(512, 1, 1);
  const float sc1 = 0.14142135623730951f;  // 1/sqrt(50)
  const float sc2 = 0.04419417382415922f;  // 1/sqrt(512)

  hipMemsetAsync(r1, 0, (size_t)4 * 4096 * 4, stream);
  hipMemsetAsync(r2, 0, (size_t)4 * 4096 * 4, stream);
  hipMemsetAsync(o1p, 0, (size_t)512 * 4096 * 4, stream);

  // ---- weight conversions
  wt_conv<<<dim3(256),  b256, 0, stream>>>(Wq1, bq1, Wqk1,             200, 200, 512, 544, 64, 50);
  wt_conv<<<dim3(256),  b256, 0, stream>>>(Wk1, bk1, Wqk1 + 256 * 544, 200, 200, 512, 544, 64, 50);
  wt_conv<<<dim3(512),  b256, 0, stream>>>(Wv1, bv1, Wv1b,             200, 200, 512, 544, 128, 50);
  wt_conv<<<dim3(512),  b256, 0, stream>>>(Ws1, bs1, Ws1p,             200, 200, 512, 544, 128, 50);
  wt_conv<<<dim3(2048), b256, 0, stream>>>(Wq2, bq2, Wqk2,              2048, 2048, 200, 256, 2048, 2048);
  wt_conv<<<dim3(2048), b256, 0, stream>>>(Wk2, bk2, Wqk2 + 2048 * 256, 2048, 2048, 200, 256, 2048, 2048);
  wt_conv<<<dim3(2048), b256, 0, stream>>>(Wv2, bv2, Wcat,              2048, 2048, 200, 256, 2048, 2048);
  wt_conv<<<dim3(2048), b256, 0, stream>>>(Ws2, bs2, Wcat + 2048 * 256, 2048, 2048, 200, 256, 2048, 2048);
  trans_pad<<<dim3(9, 64), b256, 0, stream>>>(lr_x, xb, 512, 544);

  // ---- layer-1 projections (128^2 kernel)
  mfma_bt<1, false, false><<<dim3(4, 32), b256, 0, stream>>>(
      xb, Wqk1, qk1b, 544, 544, 512, 544, 1, 0, 0, 0, -1, 0, -1, 4096, 1.f, nullptr);
  mfma_bt<1, false, false><<<dim3(32, 4), b256, 0, stream>>>(
      Wv1b, xb, v1b, 544, 544, 4096, 544, 1, 0, 0, 0, -1, 0, -1, 512, 1.f, nullptr);
  mfma_bt<0, false, false><<<dim3(32, 4), b256, 0, stream>>>(
      Ws1p, xb, s1p, 544, 544, 4096, 544, 1, 0, 0, 0, -1, 0, 127, 50, 1.f, nullptr);

  // ---- attention 1: expS scores (+rowsum) -> PV atomic -> gn1
  mfma_bt<1, false, true><<<dim3(32, 32, 4), b256, 0, stream>>>(
      qk1b, qk1b + 256, Pall, 512, 512, 4096, 64, 1,
      64, 64, PSTR, -1, 0, -1, 4096, sc1, r1);
  mfma_bt<2, false, false><<<dim3(32, 4, 8), b256, 0, stream>>>(
      v1b, Pall, o1p, 4096, 4096, 4096, 4096, 8,
      0, 0, 0, 7, PSTR, 127, 50, 1.f, nullptr);
  graph_norm_attn1<<<dim3(200), b256, 0, stream>>>(s1p, o1p, r1, h1nT, gn1w, gn1b, gn1ms);
  trans_pad<<<dim3(4, 64), b256, 0, stream>>>(h1nT, h1nb, 200, 256);

  // ---- layer-2 projections: SHORT K=256 -> 128^2 kernel (5 blocks/CU)
  mfma_bt<1, false, false><<<dim3(32, 32), b256, 0, stream>>>(
      h1nb, Wqk2, qk2b, 256, 256, 4096, 256, 1, 0, 0, 0, -1, 0, -1, 4096, 1.f, nullptr);
  mfma_bt<1, false, false><<<dim3(32, 32), b256, 0, stream>>>(
      Wcat, h1nb, vs2b, 256, 256, 4096, 256, 1, 0, 0, 0, -1, 0, -1, 4096, 1.f, nullptr);

  // ---- attention 2: expS scores (SHORT K=512 -> 128^2 kernel, z=heads)
  mfma_bt<1, false, true><<<dim3(32, 32, 4), b256, 0, stream>>>(
      qk2b, qk2b + 2048, Pall, 4096, 4096, 4096, 512, 1,
      512, 512, PSTR, -1, 0, -1, 4096, sc2, r2);
  // ---- PV-2: LONG K (Kc=2048) -> 8-phase kernel; bf16 partials (alias qk2b)
  mfma256_8ph<1, false, false><<<dim3(16, 8, 2), b512, 0, stream>>>(
      vs2b, Pall, p2, 4096, 4096, 4096, 4096, 2,
      0, 0, (size_t)2048 * 4096, 9, PSTR, 2048, 1.f, nullptr);
  graph_norm_attn2<<<dim3(2048), b256, 0, stream>>>(
      vs2b + (size_t)2048 * 4096, p2, r2, h2b, gn2w, gn2b, gn2ms);

  // ---- out = relu(h2n . h2n^T): LONG K (Kc=1024) -> 8-phase; partials+reduce
  mfma256_8ph<0, false, false><<<dim3(8, 8, 4), b512, 0, stream>>>(
      h2b, h2b, g4, 4096, 4096, 2048, 4096, 4,
      0, 0, (size_t)2048 * 2048, -1, 0, 2048, 1.f, nullptr);
  add4_relu<<<dim3(4096), b256, 0, stream>>>(g4, (float*)d_out);
}

// Round 9
// 495.729 us; speedup vs baseline: 1.0726x; 1.0549x over previous
//
#include <hip/hip_runtime.h>
#include <math.h>

typedef unsigned int u32;
typedef unsigned short ushort_t;
typedef __attribute__((ext_vector_type(8))) short short8;
typedef __attribute__((ext_vector_type(4))) float f32x4;

__device__ __forceinline__ ushort_t f2bf(float x) {
  u32 u = __float_as_uint(x);
  u32 r = (u + 0x7fffu + ((u >> 16) & 1u)) >> 16;
  return (ushort_t)r;
}
__device__ __forceinline__ float bf2f(u32 s) {
  return __uint_as_float(s << 16);
}
__device__ __forceinline__ void ld4bf(const ushort_t* p, float* o) {
  uint2 u = *(const uint2*)p;
  o[0] = bf2f(u.x & 0xffffu); o[1] = bf2f(u.x >> 16);
  o[2] = bf2f(u.y & 0xffffu); o[3] = bf2f(u.y >> 16);
}

// ---------------- block reduction helpers (256 threads = 4 waves) ----------
__device__ __forceinline__ float block_sum256(float v, float* red) {
  #pragma unroll
  for (int o = 32; o > 0; o >>= 1) v += __shfl_down(v, o, 64);
  __syncthreads();
  if ((threadIdx.x & 63) == 0) red[threadIdx.x >> 6] = v;
  __syncthreads();
  return red[0] + red[1] + red[2] + red[3];
}

// =====================================================================
// 256x256-tile, 8-phase, counted-vmcnt MFMA GEMM (m201-style schedule).
// LONG-K dispatches only (128 KiB LDS -> 1 block/CU; R7 lesson).
// C[m,n] (op)= scale * sum_k A[m,k]*B[n,k];  A:[M,K] bf16, B:[N,K] bf16.
// EXPSUM: v=exp2(v*scale) (caller folds log2e into scale); row-sums -> Rs.
// =====================================================================
#define RD_A(bb, mm, cc) (*(const short8*)(lsAc + (bb)*32768 + arow + (mm)*2048 + (cc)))
#define RD_B(bb, nn, cc) (*(const short8*)(lsBc + (bb)*32768 + brow + (nn)*2048 + (cc)))

#define MM8(nn, bv) { \
  acc[0][nn] = __builtin_amdgcn_mfma_f32_16x16x32_bf16(a0, bv, acc[0][nn], 0,0,0); \
  acc[1][nn] = __builtin_amdgcn_mfma_f32_16x16x32_bf16(a1, bv, acc[1][nn], 0,0,0); \
  acc[2][nn] = __builtin_amdgcn_mfma_f32_16x16x32_bf16(a2, bv, acc[2][nn], 0,0,0); \
  acc[3][nn] = __builtin_amdgcn_mfma_f32_16x16x32_bf16(a3, bv, acc[3][nn], 0,0,0); \
  acc[4][nn] = __builtin_amdgcn_mfma_f32_16x16x32_bf16(a4, bv, acc[4][nn], 0,0,0); \
  acc[5][nn] = __builtin_amdgcn_mfma_f32_16x16x32_bf16(a5, bv, acc[5][nn], 0,0,0); \
  acc[6][nn] = __builtin_amdgcn_mfma_f32_16x16x32_bf16(a6, bv, acc[6][nn], 0,0,0); \
  acc[7][nn] = __builtin_amdgcn_mfma_f32_16x16x32_bf16(a7, bv, acc[7][nn], 0,0,0); }

#define STG(BASE, LD, LS, bb, hf, tt) { \
  _Pragma("unroll") \
  for (int ii = 0; ii < 2; ++ii) { \
    const int s_ = t + ii * 512; \
    const int r_ = s_ >> 3; \
    const int lc_ = (s_ & 7) ^ (r_ & 7); \
    __builtin_amdgcn_global_load_lds( \
      (const __attribute__((address_space(1))) u32*)((BASE) + (size_t)((hf) * 128 + r_) * (LD) + (size_t)(tt) * 64 + lc_ * 8), \
      (__attribute__((address_space(3))) u32*)(&(LS)[bb][(hf) * 8192 + s_ * 8]), 16, 0, 0); \
  } }

#define BAR() __builtin_amdgcn_s_barrier()
#define PRIO(x) __builtin_amdgcn_s_setprio(x)

#define GRP(bf, tS1, tS2) { \
  a0=RD_A(bf,0,c0); a1=RD_A(bf,1,c0); a2=RD_A(bf,2,c0); a3=RD_A(bf,3,c0); \
  a4=RD_A(bf,4,c0); a5=RD_A(bf,5,c0); a6=RD_A(bf,6,c0); a7=RD_A(bf,7,c0); \
  b0=RD_B(bf,0,c0); b1=RD_B(bf,1,c0); \
  STG(Ab, lda, lsA, 1-(bf), 1, tS1); STG(Bb, ldb, lsB, 1-(bf), 0, tS1); \
  BAR(); PRIO(1); MM8(0, b0); MM8(1, b1); PRIO(0); BAR(); \
  b2=RD_B(bf,2,c0); b3=RD_B(bf,3,c0); \
  STG(Bb, ldb, lsB, 1-(bf), 1, tS1); \
  BAR(); PRIO(1); MM8(2, b2); MM8(3, b3); PRIO(0); BAR(); \
  a0=RD_A(bf,0,c1); a1=RD_A(bf,1,c1); a2=RD_A(bf,2,c1); a3=RD_A(bf,3,c1); \
  a4=RD_A(bf,4,c1); a5=RD_A(bf,5,c1); a6=RD_A(bf,6,c1); a7=RD_A(bf,7,c1); \
  b0=RD_B(bf,0,c1); b1=RD_B(bf,1,c1); \
  BAR(); PRIO(1); MM8(0, b0); MM8(1, b1); PRIO(0); BAR(); \
  b2=RD_B(bf,2,c1); b3=RD_B(bf,3,c1); \
  STG(Ab, lda, lsA, (bf), 0, tS2); \
  BAR(); PRIO(1); MM8(2, b2); MM8(3, b3); PRIO(0); \
  asm volatile("s_waitcnt vmcnt(2)" ::: "memory"); \
  BAR(); }

template<int CMODE, bool RELU, bool EXPSUM>
__global__ __launch_bounds__(512, 2) void mfma256_8ph(
    const ushort_t* __restrict__ A, const ushort_t* __restrict__ B,
    void* __restrict__ Cv, int lda, int ldb, int ldc,
    int K, int zsplit, size_t zA, size_t zB, size_t zC,
    int bShift, size_t bHead, int Mvalid, float scale,
    float* __restrict__ Rs)
{
  __shared__ ushort_t lsA[2][16384];
  __shared__ ushort_t lsB[2][16384];
  const int t = threadIdx.x;
  const int gx = gridDim.x;
  const int nwg = gx * gridDim.y;
  const int bid = blockIdx.y * gx + blockIdx.x;
  const int qq = nwg >> 3, rr_ = nwg & 7;
  const int xcd = bid & 7, idx = bid >> 3;
  const int swz = (xcd < rr_ ? xcd * (qq + 1) : rr_ * (qq + 1) + (xcd - rr_) * qq) + idx;
  const int m0 = (swz / gx) * 256;
  const int n0 = (swz % gx) * 256;
  const int z = blockIdx.z;
  int Kc = K, kOff = 0;
  size_t aZ = 0, bZ = 0, cZ = 0;
  if (zsplit > 1) { Kc = K / zsplit; kOff = z * Kc; cZ = (size_t)z * zC; }
  else { aZ = (size_t)z * zA; bZ = (size_t)z * zB; cZ = (size_t)z * zC; }
  const ushort_t* Ab = A + aZ + (size_t)m0 * lda + kOff;
  const ushort_t* Bb = B + bZ + (size_t)n0 * ldb + kOff
                     + (bShift >= 0 ? (size_t)(m0 >> bShift) * bHead : 0);
  const int NT = Kc / 64;

  f32x4 acc[8][4];
  #pragma unroll
  for (int i = 0; i < 8; ++i)
    #pragma unroll
    for (int j = 0; j < 4; ++j) acc[i][j] = (f32x4){0.f, 0.f, 0.f, 0.f};

  const int lane = t & 63;
  const int wv = t >> 6;
  const int wr = (wv >> 2) * 128;
  const int wc = (wv & 3) * 64;
  const int lr = lane & 15;
  const int kc = lane >> 4;
  const int sw = lane & 7;
  const int c0 = (kc ^ sw) * 16;
  const int c1 = c0 ^ 64;
  const int arow = (wr + lr) * 128;
  const int brow = (wc + lr) * 128;
  const char* lsAc = (const char*)lsA;
  const char* lsBc = (const char*)lsB;

  short8 a0, a1, a2, a3, a4, a5, a6, a7, b0, b1, b2, b3;

  STG(Ab, lda, lsA, 0, 0, 0); STG(Ab, lda, lsA, 0, 1, 0);
  STG(Bb, ldb, lsB, 0, 0, 0); STG(Bb, ldb, lsB, 0, 1, 0);
  STG(Ab, lda, lsA, 1, 0, 1);
  asm volatile("s_waitcnt vmcnt(2)" ::: "memory");
  BAR();

  const int NITER = NT >> 1;
  for (int it = 0; it < NITER; ++it) {
    const int tb = 2 * it;
    const int s1 = tb + 1;
    const int s2 = (tb + 2 < NT) ? tb + 2 : 0;
    const int s3 = (tb + 3 < NT) ? tb + 3 : 0;
    GRP(0, s1, s2)
    GRP(1, s2, s3)
  }

  const int row4 = (lane >> 4) * 4;
  const int coln = lane & 15;
  float* Cf = (float*)Cv + cZ;
  ushort_t* Ch = (ushort_t*)Cv + cZ;
  float* rs = EXPSUM ? (Rs + (size_t)z * 4096) : nullptr;
  #pragma unroll
  for (int m = 0; m < 8; ++m) {
    #pragma unroll
    for (int r = 0; r < 4; ++r) {
      const int gm = m0 + wr + m * 16 + row4 + r;
      const bool ok = gm < Mvalid;
      float rowpart = 0.f;
      #pragma unroll
      for (int n = 0; n < 4; ++n) {
        const int gn = n0 + wc + n * 16 + coln;
        float v = acc[m][n][r] * scale;
        if (EXPSUM) { v = exp2f(v); rowpart += v; }
        if (RELU) v = fmaxf(v, 0.f);
        if (ok) {
          if (CMODE == 0)      Cf[(size_t)gm * ldc + gn] = v;
          else if (CMODE == 1) Ch[(size_t)gm * ldc + gn] = f2bf(v);
          else                 atomicAdd(&Cf[(size_t)gm * ldc + gn], v);
        }
      }
      if (EXPSUM) {
        rowpart += __shfl_xor(rowpart, 1);
        rowpart += __shfl_xor(rowpart, 2);
        rowpart += __shfl_xor(rowpart, 4);
        rowpart += __shfl_xor(rowpart, 8);
        if (ok && (lane & 15) == 0) atomicAdd(&rs[gm], rowpart);
      }
    }
  }
}

#undef GRP
#undef STG
#undef MM8
#undef RD_A
#undef RD_B

// ================= 128x128-tile MFMA GEMM, 256 threads =====================
// 32 KiB LDS -> ~5 blocks/CU: for SHORT-K dispatches (R7 lesson).
template<int CMODE, bool RELU, bool EXPSUM>
__global__ __launch_bounds__(256) void mfma_bt(
    const ushort_t* __restrict__ A, const ushort_t* __restrict__ B,
    void* __restrict__ Cv, int lda, int ldb, int ldc,
    int K, int Ksplit, size_t zA, size_t zB, size_t zC,
    int bShift, size_t bHead, int mMask, int Mvalid, float scale,
    float* __restrict__ Rs)
{
  __shared__ ushort_t lsA[2][128 * 32];
  __shared__ ushort_t lsB[2][128 * 32];
  const int t  = threadIdx.x;
  const int m0 = blockIdx.y * 128;
  const int n0 = blockIdx.x * 128;
  const int z = blockIdx.z;
  int Kc = K, kOff = 0;
  size_t aZ = 0, bZ = 0, cZ = 0;
  if (Ksplit > 1) { Kc = K / Ksplit; kOff = z * Kc; cZ = (size_t)z * zC; }
  else { aZ = (size_t)z * zA; bZ = (size_t)z * zB; cZ = (size_t)z * zC; }
  const int NT = Kc / 32;
  const ushort_t* Ab = A + aZ + (size_t)m0 * lda + kOff;
  const ushort_t* Bb = B + bZ + (size_t)n0 * ldb + kOff
                     + (bShift >= 0 ? (size_t)(m0 >> bShift) * bHead : 0);
  const int cs = t & 3;

  f32x4 acc[4][4];
  #pragma unroll
  for (int i = 0; i < 4; ++i)
    #pragma unroll
    for (int j = 0; j < 4; ++j) acc[i][j] = (f32x4){0.f, 0.f, 0.f, 0.f};

  const int lane = t & 63;
  const int wv = t >> 6;
  const int wr = (wv >> 1) * 64;
  const int wc = (wv & 1) * 64;
  const int lr = lane & 15;
  const int kc = lane >> 4;

  int roffA[4], roffB[4];
  #pragma unroll
  for (int m = 0; m < 4; ++m) {
    int ra = wr + m * 16 + lr;
    roffA[m] = ra * 64 + ((kc ^ (ra & 3)) * 16);
    int rb = wc + m * 16 + lr;
    roffB[m] = rb * 64 + ((kc ^ (rb & 3)) * 16);
  }

  auto stage = [&](int buf, int kt) {
    const ushort_t* As = Ab + kt * 32;
    const ushort_t* Bs = Bb + kt * 32;
    #pragma unroll
    for (int i = 0; i < 2; ++i) {
      int s = t + i * 256;
      int r = s >> 2;
      int c = cs ^ (r & 3);
      __builtin_amdgcn_global_load_lds(
          (const __attribute__((address_space(1))) u32*)(As + (size_t)r * lda + c * 8),
          (__attribute__((address_space(3))) u32*)(&lsA[buf][s * 8]), 16, 0, 0);
    }
    #pragma unroll
    for (int i = 0; i < 2; ++i) {
      int s = t + i * 256;
      int r = s >> 2;
      int c = cs ^ (r & 3);
      __builtin_amdgcn_global_load_lds(
          (const __attribute__((address_space(1))) u32*)(Bs + (size_t)r * ldb + c * 8),
          (__attribute__((address_space(3))) u32*)(&lsB[buf][s * 8]), 16, 0, 0);
    }
  };

  stage(0, 0);
  __syncthreads();
  int cur = 0;
  for (int kt = 0; kt < NT; ++kt) {
    if (kt + 1 < NT) stage(cur ^ 1, kt + 1);
    short8 af[4], bfr[4];
    const char* baseA = (const char*)&lsA[cur][0];
    const char* baseB = (const char*)&lsB[cur][0];
    #pragma unroll
    for (int m = 0; m < 4; ++m) af[m]  = *(const short8*)(baseA + roffA[m]);
    #pragma unroll
    for (int n = 0; n < 4; ++n) bfr[n] = *(const short8*)(baseB + roffB[n]);
    #pragma unroll
    for (int m = 0; m < 4; ++m)
      #pragma unroll
      for (int n = 0; n < 4; ++n)
        acc[m][n] = __builtin_amdgcn_mfma_f32_16x16x32_bf16(af[m], bfr[n], acc[m][n], 0, 0, 0);
    __syncthreads();
    cur ^= 1;
  }

  const int row4 = (lane >> 4) * 4;
  const int coln = lane & 15;
  float* Cf = (float*)Cv + cZ;
  ushort_t* Ch = (ushort_t*)Cv + cZ;
  float* rs = EXPSUM ? (Rs + (size_t)z * 4096) : nullptr;
  #pragma unroll
  for (int m = 0; m < 4; ++m) {
    #pragma unroll
    for (int r = 0; r < 4; ++r) {
      const int gm = m0 + wr + m * 16 + row4 + r;
      const bool ok = (mMask >= 0) ? ((gm & mMask) < Mvalid) : (gm < Mvalid);
      float rowpart = 0.f;
      #pragma unroll
      for (int n = 0; n < 4; ++n) {
        const int gn = n0 + wc + n * 16 + coln;
        float v = acc[m][n][r] * scale;
        if (EXPSUM) { v = exp2f(v); rowpart += v; }
        if (RELU) v = fmaxf(v, 0.f);
        if (ok) {
          if (CMODE == 0)      Cf[(size_t)gm * ldc + gn] = v;
          else if (CMODE == 1) Ch[(size_t)gm * ldc + gn] = f2bf(v);
          else                 atomicAdd(&Cf[(size_t)gm * ldc + gn], v);
        }
      }
      if (EXPSUM) {
        rowpart += __shfl_xor(rowpart, 1);
        rowpart += __shfl_xor(rowpart, 2);
        rowpart += __shfl_xor(rowpart, 4);
        rowpart += __shfl_xor(rowpart, 8);
        if (ok && (lane & 15) == 0) atomicAdd(&rs[gm], rowpart);
      }
    }
  }
}

// ---------------- weights: dst[Mp,Kp] bf16 = W^T (+ bias slot at k==Kv) ----
__global__ __launch_bounds__(256) void wt_conv(
    const float* __restrict__ W, const float* __restrict__ bias,
    ushort_t* __restrict__ dst, int Mtot, int ldw, int Kv, int Kp,
    int PADH, int VALH)
{
  const int m = blockIdx.x;
  const int h = m / PADH, c0 = m % PADH;
  const int fout = h * VALH + c0;
  const bool valid = (c0 < VALH) && (fout < Mtot);
  for (int k = threadIdx.x; k < Kp; k += blockDim.x) {
    float v = 0.f;
    if (valid) {
      if (k < Kv) v = W[(size_t)k * ldw + fout];
      else if (k == Kv) v = bias[fout];
    }
    dst[(size_t)m * Kp + k] = f2bf(v);
  }
}

// ---------------- wt_trans: dst[4][256][512] bf16; dst[h][a][f] =
// a<200 ? W[a, h*512+f] : (a==200 ? bias[h*512+f] : 0). W is [200, 2048].
__global__ __launch_bounds__(256) void wt_trans(
    const float* __restrict__ W, const float* __restrict__ bias,
    ushort_t* __restrict__ dst)
{
  const int rid = blockIdx.x;          // 0..1023
  const int h = rid >> 8, a = rid & 255;
  for (int f = threadIdx.x; f < 512; f += 256) {
    float v = 0.f;
    if (a < 200)       v = W[(size_t)a * 2048 + h * 512 + f];
    else if (a == 200) v = bias[h * 512 + f];
    dst[(size_t)rid * 512 + f] = f2bf(v);
  }
}

// ---------------- transpose fp32 [Kv,4096] -> bf16 [4096,Kp], bias slot ----
__global__ __launch_bounds__(256) void trans_pad(
    const float* __restrict__ src, ushort_t* __restrict__ dst, int Kv, int Kp)
{
  __shared__ float tl[64][65];
  const int t = threadIdx.x;
  const int f0 = blockIdx.x * 64;
  const int i0 = blockIdx.y * 64;
  const int c = t & 63, rbase = t >> 6;
  #pragma unroll
  for (int it = 0; it < 16; ++it) {
    int r = rbase + it * 4;
    int f = f0 + r;
    tl[r][c] = (f < Kv) ? src[(size_t)f * 4096 + i0 + c] : 0.f;
  }
  __syncthreads();
  #pragma unroll
  for (int it = 0; it < 16; ++it) {
    int r = rbase + it * 4;
    int f = f0 + c;
    if (f < Kp) {
      float v = (f < Kv) ? tl[c][r] : ((f == Kv) ? 1.f : 0.f);
      dst[(size_t)(i0 + r) * Kp + f] = f2bf(v);
    }
  }
}

// ---------------- GraphNorm layer 1: x = skip + attn/r, gn, f32 out --------
__global__ __launch_bounds__(256) void graph_norm_attn1(
    const float* __restrict__ skip, const float* __restrict__ attn,
    const float* __restrict__ r1, float* __restrict__ out,
    const float* __restrict__ w, const float* __restrict__ b,
    const float* __restrict__ ms)
{
  __shared__ float red[4];
  const int t = threadIdx.x;
  const int row = blockIdx.x;            // 0..199
  const int pr = (row / 50) * 128 + row % 50;
  const float* sk = skip + (size_t)pr * 4096;
  const float* at = attn + (size_t)pr * 4096;
  const float* rr = r1 + (size_t)(row / 50) * 4096;
  float v[16];
  float s = 0.f;
  #pragma unroll
  for (int e = 0; e < 4; ++e) {
    const int idx = t * 4 + 1024 * e;
    float4 a = *(const float4*)&sk[idx];
    float4 o = *(const float4*)&at[idx];
    float4 rv = *(const float4*)&rr[idx];
    v[e*4+0] = a.x + o.x / rv.x; v[e*4+1] = a.y + o.y / rv.y;
    v[e*4+2] = a.z + o.z / rv.z; v[e*4+3] = a.w + o.w / rv.w;
    s += v[e*4+0] + v[e*4+1] + v[e*4+2] + v[e*4+3];
  }
  const float mean = block_sum256(s, red) * (1.f / 4096.f);
  const float sub = mean * ms[row];
  float s2 = 0.f;
  #pragma unroll
  for (int e = 0; e < 16; ++e) { v[e] -= sub; s2 += v[e] * v[e]; }
  const float var = block_sum256(s2, red) * (1.f / 4096.f);
  const float scl = rsqrtf(var + 1e-5f) * w[row];
  const float bb = b[row];
  float* y = out + (size_t)row * 4096;
  #pragma unroll
  for (int e = 0; e < 4; ++e) {
    float o0[4];
    #pragma unroll
    for (int q = 0; q < 4; ++q) o0[q] = v[e * 4 + q] * scl + bb;
    *(float4*)&y[t * 4 + 1024 * e] = *(float4*)&o0[0];
  }
}

// ---------------- GraphNorm layer 2: x = skip + (p0+p1)/r, gn, L2, bf16 ----
__global__ __launch_bounds__(256) void graph_norm_attn2(
    const ushort_t* __restrict__ skip, const ushort_t* __restrict__ p2,
    const float* __restrict__ r2, ushort_t* __restrict__ out,
    const float* __restrict__ w, const float* __restrict__ b,
    const float* __restrict__ ms)
{
  __shared__ float red[4];
  const int t = threadIdx.x;
  const int row = blockIdx.x;            // 0..2047
  const ushort_t* sk = skip + (size_t)row * 4096;
  const ushort_t* pa = p2 + (size_t)row * 4096;
  const ushort_t* pb = p2 + (size_t)2048 * 4096 + (size_t)row * 4096;
  const float* rr = r2 + (size_t)(row >> 9) * 4096;
  float v[16];
  float s = 0.f;
  #pragma unroll
  for (int e = 0; e < 4; ++e) {
    const int idx = t * 4 + 1024 * e;
    float a[4], oa[4], ob[4];
    ld4bf(&sk[idx], a); ld4bf(&pa[idx], oa); ld4bf(&pb[idx], ob);
    float4 rv = *(const float4*)&rr[idx];
    v[e*4+0] = a[0] + (oa[0] + ob[0]) / rv.x;
    v[e*4+1] = a[1] + (oa[1] + ob[1]) / rv.y;
    v[e*4+2] = a[2] + (oa[2] + ob[2]) / rv.z;
    v[e*4+3] = a[3] + (oa[3] + ob[3]) / rv.w;
    s += v[e*4+0] + v[e*4+1] + v[e*4+2] + v[e*4+3];
  }
  const float mean = block_sum256(s, red) * (1.f / 4096.f);
  const float sub = mean * ms[row];
  float s2 = 0.f;
  #pragma unroll
  for (int e = 0; e < 16; ++e) { v[e] -= sub; s2 += v[e] * v[e]; }
  const float var = block_sum256(s2, red) * (1.f / 4096.f);
  const float scl = rsqrtf(var + 1e-5f) * w[row];
  const float bb = b[row];
  #pragma unroll
  for (int e = 0; e < 16; ++e) v[e] = v[e] * scl + bb;
  float s3 = 0.f;
  #pragma unroll
  for (int e = 0; e < 16; ++e) s3 += v[e] * v[e];
  const float osc = rsqrtf(block_sum256(s3, red));
  ushort_t* y = out + (size_t)row * 4096;
  #pragma unroll
  for (int e = 0; e < 4; ++e) {
    ushort_t o0[4];
    #pragma unroll
    for (int q = 0; q < 4; ++q) o0[q] = f2bf(v[e * 4 + q] * osc);
    *(ushort2*)&y[t * 4 + 1024 * e] = *(ushort2*)&o0[0];
    *(ushort2*)&y[t * 4 + 1024 * e + 2] = *(ushort2*)&o0[2];
  }
}

// ---------------- out = relu(g0+g1+g2+g3), float4-wide ---------------------
__global__ __launch_bounds__(256) void add4_relu(
    const float* __restrict__ g, float* __restrict__ out)
{
  const size_t i = (size_t)blockIdx.x * 256 + threadIdx.x;
  const size_t ss = (size_t)2048 * 2048 / 4;
  float4 a = ((const float4*)g)[i];
  float4 b = ((const float4*)g)[i + ss];
  float4 c = ((const float4*)g)[i + 2 * ss];
  float4 d = ((const float4*)g)[i + 3 * ss];
  float4 o;
  o.x = fmaxf(a.x + b.x + c.x + d.x, 0.f);
  o.y = fmaxf(a.y + b.y + c.y + d.y, 0.f);
  o.z = fmaxf(a.z + b.z + c.z + d.z, 0.f);
  o.w = fmaxf(a.w + b.w + c.w + d.w, 0.f);
  ((float4*)out)[i] = o;
}

extern "C" void kernel_launch(void* const* d_in, const int* in_sizes, int n_in,
                              void* d_out, int out_size, void* d_ws, size_t ws_size,
                              hipStream_t stream)
{
  (void)in_sizes; (void)n_in; (void)out_size; (void)ws_size;
  const float* lr_x = (const float*)d_in[0];
  const float* Wq1 = (const float*)d_in[1];  const float* bq1 = (const float*)d_in[2];
  const float* Wk1 = (const float*)d_in[3];  const float* bk1 = (const float*)d_in[4];
  const float* Wv1 = (const float*)d_in[5];  const float* bv1 = (const float*)d_in[6];
  const float* Ws1 = (const float*)d_in[7];  const float* bs1 = (const float*)d_in[8];
  const float* gn1w = (const float*)d_in[9]; const float* gn1b = (const float*)d_in[10];
  const float* gn1ms = (const float*)d_in[11];
  const float* Wq2 = (const float*)d_in[12]; const float* bq2 = (const float*)d_in[13];
  const float* Wk2 = (const float*)d_in[14]; const float* bk2 = (const float*)d_in[15];
  const float* Wv2 = (const float*)d_in[16]; const float* bv2 = (const float*)d_in[17];
  const float* Ws2 = (const float*)d_in[18]; const float* bs2 = (const float*)d_in[19];
  const float* gn2w = (const float*)d_in[20]; const float* gn2b = (const float*)d_in[21];
  const float* gn2ms = (const float*)d_in[22];

  // ---- workspace carve (~251 MB total, < 256 MiB cap) ----
  char* p = (char*)d_ws;
  auto alloc = [&](size_t bytes) { char* r = p; p += (bytes + 255) & ~(size_t)255; return r; };
  const size_t PSTR = (size_t)4096 * 4096;
  ushort_t* Pall = (ushort_t*)alloc(PSTR * 4 * 2);              // 134.2 MB; Gram partials alias
  ushort_t* xb   = (ushort_t*)alloc((size_t)4096 * 544 * 2);
  ushort_t* qk1b = (ushort_t*)alloc((size_t)4096 * 512 * 2);
  ushort_t* v1b  = (ushort_t*)alloc((size_t)512 * 4096 * 2);
  char*     u0   = alloc((size_t)16 * 1024 * 1024);             // s1p+o1p, later h2b
  float*    s1p  = (float*)u0;                                  // [512,4096] f32 skip
  float*    o1p  = (float*)(u0 + (size_t)8 * 1024 * 1024);      // [512,4096] f32 attn accum
  float*    h1nT = (float*)   alloc((size_t)200 * 4096 * 4);
  ushort_t* h1nb = (ushort_t*)alloc((size_t)4096 * 256 * 2);
  ushort_t* Wqk1 = (ushort_t*)alloc((size_t)512 * 544 * 2);
  ushort_t* Wv1b = (ushort_t*)alloc((size_t)512 * 544 * 2);
  ushort_t* Ws1p = (ushort_t*)alloc((size_t)512 * 544 * 2);
  ushort_t* Wcat = (ushort_t*)alloc((size_t)4096 * 256 * 2);    // [v2 | s2] weights
  ushort_t* Qt   = (ushort_t*)alloc((size_t)4 * 256 * 512 * 2); // per-head W~q^T [256,512]
  ushort_t* Kt   = (ushort_t*)alloc((size_t)4 * 256 * 512 * 2); // per-head W~k^T [256,512]
  ushort_t* Mtall= (ushort_t*)alloc((size_t)4 * 256 * 256 * 2); // per-head M^T [256,256]
  ushort_t* Tall = (ushort_t*)alloc((size_t)4 * 4096 * 256 * 2);// per-head T=XM [4096,256]
  ushort_t* vs2b = (ushort_t*)alloc((size_t)4096 * 4096 * 2);   // rows 0..2047=v2T, 2048..4095=skip2
  ushort_t* p2   = (ushort_t*)alloc((size_t)2 * 2048 * 4096 * 2);// PV-2 partials bf16
  float*    r1   = (float*)   alloc((size_t)4 * 4096 * 4);
  float*    r2   = (float*)   alloc((size_t)4 * 4096 * 4);
  // aliases (regions dead by the time the alias is written):
  ushort_t* h2b  = (ushort_t*)u0;  // gn2 output: s1p/o1p dead after gn1
  float*    g4   = (float*)Pall;   // Gram partials: Pall dead after PV-2

  const dim3 b256(256, 1, 1);
  const dim3 b512(512, 1, 1);
  const float LOG2E = 1.4426950408889634f;
  const float sc1e = 0.14142135623730951f * LOG2E;  // 1/sqrt(50) * log2e
  const float sc2e = 0.04419417382415922f * LOG2E;  // 1/sqrt(512) * log2e

  hipMemsetAsync(r1, 0, (size_t)4 * 4096 * 4, stream);
  hipMemsetAsync(r2, 0, (size_t)4 * 4096 * 4, stream);
  hipMemsetAsync(o1p, 0, (size_t)512 * 4096 * 4, stream);

  // ---- weight conversions
  wt_conv<<<dim3(256),  b256, 0, stream>>>(Wq1, bq1, Wqk1,             200, 200, 512, 544, 64, 50);
  wt_conv<<<dim3(256),  b256, 0, stream>>>(Wk1, bk1, Wqk1 + 256 * 544, 200, 200, 512, 544, 64, 50);
  wt_conv<<<dim3(512),  b256, 0, stream>>>(Wv1, bv1, Wv1b,             200, 200, 512, 544, 128, 50);
  wt_conv<<<dim3(512),  b256, 0, stream>>>(Ws1, bs1, Ws1p,             200, 200, 512, 544, 128, 50);
  wt_conv<<<dim3(2048), b256, 0, stream>>>(Wv2, bv2, Wcat,              2048, 2048, 200, 256, 2048, 2048);
  wt_conv<<<dim3(2048), b256, 0, stream>>>(Ws2, bs2, Wcat + 2048 * 256, 2048, 2048, 200, 256, 2048, 2048);
  wt_trans<<<dim3(1024), b256, 0, stream>>>(Wq2, bq2, Qt);
  wt_trans<<<dim3(1024), b256, 0, stream>>>(Wk2, bk2, Kt);
  trans_pad<<<dim3(9, 64), b256, 0, stream>>>(lr_x, xb, 512, 544);

  // ---- layer-1 projections (128^2 kernel)
  mfma_bt<1, false, false><<<dim3(4, 32), b256, 0, stream>>>(
      xb, Wqk1, qk1b, 544, 544, 512, 544, 1, 0, 0, 0, -1, 0, -1, 4096, 1.f, nullptr);
  mfma_bt<1, false, false><<<dim3(32, 4), b256, 0, stream>>>(
      Wv1b, xb, v1b, 544, 544, 4096, 544, 1, 0, 0, 0, -1, 0, -1, 512, 1.f, nullptr);
  mfma_bt<0, false, false><<<dim3(32, 4), b256, 0, stream>>>(
      Ws1p, xb, s1p, 544, 544, 4096, 544, 1, 0, 0, 0, -1, 0, 127, 50, 1.f, nullptr);

  // ---- attention 1: expS scores (+rowsum) -> PV atomic -> gn1
  mfma_bt<1, false, true><<<dim3(32, 32, 4), b256, 0, stream>>>(
      qk1b, qk1b + 256, Pall, 512, 512, 4096, 64, 1,
      64, 64, PSTR, -1, 0, -1, 4096, sc1e, r1);
  mfma_bt<2, false, false><<<dim3(32, 4, 8), b256, 0, stream>>>(
      v1b, Pall, o1p, 4096, 4096, 4096, 4096, 8,
      0, 0, 0, 7, PSTR, 127, 50, 1.f, nullptr);
  graph_norm_attn1<<<dim3(200), b256, 0, stream>>>(s1p, o1p, r1, h1nT, gn1w, gn1b, gn1ms);
  trans_pad<<<dim3(4, 64), b256, 0, stream>>>(h1nT, h1nb, 200, 256);

  // ---- layer-2 V+skip projection (K=256, 128^2 kernel)
  mfma_bt<1, false, false><<<dim3(32, 32), b256, 0, stream>>>(
      Wcat, h1nb, vs2b, 256, 256, 4096, 256, 1, 0, 0, 0, -1, 0, -1, 4096, 1.f, nullptr);

  // ---- attention 2 scores via low-rank factorization:
  // Mt_h = Kt_h . Qt_h^T  [256,256] per head  (Mt[b,a] = M[a,b])
  mfma_bt<1, false, false><<<dim3(2, 2, 4), b256, 0, stream>>>(
      Kt, Qt, Mtall, 512, 512, 256, 512, 1,
      (size_t)256 * 512, (size_t)256 * 512, (size_t)256 * 256, -1, 0, -1, 256, 1.f, nullptr);
  // T_h = X . M_h  [4096,256]  (A=X shared across heads, B=Mt_h)
  mfma_bt<1, false, false><<<dim3(2, 32, 4), b256, 0, stream>>>(
      h1nb, Mtall, Tall, 256, 256, 256, 256, 1,
      0, (size_t)256 * 256, (size_t)4096 * 256, -1, 0, -1, 4096, 1.f, nullptr);
  // S_h = exp2(sc * T_h . X^T) (+rowsums)  — K=256 instead of 512
  mfma_bt<1, false, true><<<dim3(32, 32, 4), b256, 0, stream>>>(
      Tall, h1nb, Pall, 256, 256, 4096, 256, 1,
      (size_t)4096 * 256, 0, PSTR, -1, 0, -1, 4096, sc2e, r2);

  // ---- PV-2: LONG K (Kc=2048) -> 8-phase kernel; bf16 partials
  mfma256_8ph<1, false, false><<<dim3(16, 8, 2), b512, 0, stream>>>(
      vs2b, Pall, p2, 4096, 4096, 4096, 4096, 2,
      0, 0, (size_t)2048 * 4096, 9, PSTR, 2048, 1.f, nullptr);
  graph_norm_attn2<<<dim3(2048), b256, 0, stream>>>(
      vs2b + (size_t)2048 * 4096, p2, r2, h2b, gn2w, gn2b, gn2ms);

  // ---- out = relu(h2n . h2n^T): LONG K (Kc=1024) -> 8-phase; partials+reduce
  mfma256_8ph<0, false, false><<<dim3(8, 8, 4), b512, 0, stream>>>(
      h2b, h2b, g4, 4096, 4096, 2048, 4096, 4,
      0, 0, (size_t)2048 * 2048, -1, 0, 2048, 1.f, nullptr);
  add4_relu<<<dim3(4096), b256, 0, stream>>>(g4, (float*)d_out);
}